// Round 1
// baseline (3670.752 us; speedup 1.0000x reference)
//
#include <hip/hip_runtime.h>
#include <cstdint>
#include <cstddef>

#define NE 50000           // N entities
#define NR 400             // R relations
#define DD 300             // D
#define NTOT 50400         // N + R
#define EE 800000          // edges
#define BB 2048            // batch
#define LL 32              // seq len
#define HD 256             // H*DK

// ---------------------------------------------------------------------------
// utility kernels
// ---------------------------------------------------------------------------

__global__ void copy_f4_kernel(const float4* __restrict__ src, float4* __restrict__ dst, int n4) {
  int i = blockIdx.x * blockDim.x + threadIdx.x;
  if (i < n4) dst[i] = src[i];
}

// r0 = r_x @ Wrel + brel  -> out (R x D)
__global__ void rel_proj_kernel(const float* __restrict__ r_x, const float* __restrict__ Wrel,
                                const float* __restrict__ brel, float* __restrict__ out) {
  int row = blockIdx.x;
  int c = threadIdx.x;
  if (c >= DD) return;
  float acc = brel[c];
  const float* rr = r_x + (size_t)row * (2 * DD);
  for (int k = 0; k < 2 * DD; ++k) acc += rr[k] * Wrel[(size_t)k * DD + c];
  out[(size_t)row * DD + c] = acc;
}

__global__ void hist_kernel(const int* __restrict__ dst, int* __restrict__ counts) {
  int e = blockIdx.x * blockDim.x + threadIdx.x;
  if (e < EE) atomicAdd(&counts[dst[e]], 1);
}

// single-block exclusive scan of counts[NTOT] -> row_ptr, cursor
__global__ __launch_bounds__(1024) void scan_kernel(const int* __restrict__ counts,
                                                    int* __restrict__ row_ptr,
                                                    int* __restrict__ cursor) {
  __shared__ int sums[1024];
  const int n = NTOT;
  int t = threadIdx.x;
  const int chunk = (n + 1023) / 1024;
  int begin = t * chunk;
  int end = begin + chunk; if (end > n) end = n;
  int s = 0;
  for (int i = begin; i < end && i < n; ++i) s += counts[i];
  sums[t] = s;
  __syncthreads();
  for (int off = 1; off < 1024; off <<= 1) {
    int v = (t >= off) ? sums[t - off] : 0;
    __syncthreads();
    sums[t] += v;
    __syncthreads();
  }
  int run = sums[t] - s;   // exclusive prefix of this thread's chunk
  for (int i = begin; i < end && i < n; ++i) {
    row_ptr[i] = run; cursor[i] = run;
    run += counts[i];
  }
  if (t == 1023) row_ptr[n] = sums[1023];
}

__global__ void scatter_kernel(const int* __restrict__ dst, int* __restrict__ cursor,
                               int* __restrict__ edge_idx) {
  int e = blockIdx.x * blockDim.x + threadIdx.x;
  if (e < EE) {
    int pos = atomicAdd(&cursor[dst[e]], 1);
    edge_idx[pos] = e;
  }
}

// out[d,:] = sum_{edges e with dst==d} w[e] * feat[src[e],:]
__global__ void aggregate_kernel(const float* __restrict__ feat, float* __restrict__ out,
                                 const int* __restrict__ row_ptr, const int* __restrict__ edge_idx,
                                 const int* __restrict__ src, const float* __restrict__ w) {
  int d = blockIdx.x;
  int f = threadIdx.x;
  if (f >= DD) return;
  int beg = row_ptr[d], end = row_ptr[d + 1];
  float acc = 0.f;
  for (int e = beg; e < end; ++e) {
    int idx = edge_idx[e];
    acc += w[idx] * feat[(size_t)src[idx] * DD + f];
  }
  out[(size_t)d * DD + f] = acc;
}

// mask dtype detection: any 32-bit word > 1 => masks are byte-bools
__global__ void detect_mask_kernel(const unsigned* __restrict__ m0, const unsigned* __restrict__ m1,
                                   const unsigned* __restrict__ m2, const unsigned* __restrict__ m3,
                                   int* __restrict__ flag) {
  int idx = blockIdx.x * blockDim.x + threadIdx.x;
  const int wp = BB * LL / 4;  // 16384 words per array (safe for both dtypes)
  if (idx >= 4 * wp) return;
  const unsigned* p = idx < wp ? m0 : idx < 2 * wp ? m1 : idx < 3 * wp ? m2 : m3;
  if (p[idx % wp] > 1u) atomicOr(flag, 1);
}

__global__ void norm_mask_kernel(const void* __restrict__ raw, int* __restrict__ outm,
                                 int* __restrict__ many, const int* __restrict__ flag) {
  int idx = blockIdx.x * blockDim.x + threadIdx.x;
  if (idx >= BB * LL) return;
  int v = (*flag) ? (int)((const unsigned char*)raw)[idx] : ((const int*)raw)[idx];
  v = v ? 1 : 0;
  outm[idx] = v;
  if (v) atomicOr(&many[idx >> 5], 1);   // idx / LL
}

// ---------------------------------------------------------------------------
// generic tiled fp32 GEMM: C[M x Nn] = gather(A)[M x K] @ B[K x Nn] (+bias)(relu)
// 64x64 tile, 256 threads, 4x4 per thread.
// g1 != nullptr : A row r comes from A[g1[r]*K + k]
// btrans        : B is stored [Nn x K] row-major (B^T access)
// rowmask       : if rowmask[r]==0 write 0 for that row
// ---------------------------------------------------------------------------
__global__ __launch_bounds__(256) void gemm64_kernel(
    const float* __restrict__ A, const float* __restrict__ Bm,
    const float* __restrict__ bias, float* __restrict__ C,
    int M, int Nn, int K, int ldc, int coloff,
    const int* __restrict__ g1, int btrans, int dorelu,
    const int* __restrict__ rowmask) {
  __shared__ float As[16][68];
  __shared__ float Bs[16][68];
  int tid = threadIdx.x;
  int row0 = blockIdx.y * 64;
  int n0 = blockIdx.x * 64;
  int ty = tid >> 4, tx = tid & 15;
  float acc[4][4] = {{0.f}};
  for (int k0 = 0; k0 < K; k0 += 16) {
#pragma unroll
    for (int i = 0; i < 4; ++i) {
      int lin = tid + (i << 8);
      // A element (row0 + r, k0 + kk) -> As[kk][r]
      int r = lin >> 4, kk = lin & 15;
      int row = row0 + r, k = k0 + kk;
      float v = 0.f;
      if (row < M && k < K) {
        int ar = g1 ? g1[row] : row;
        v = A[(size_t)ar * K + k];
      }
      As[kk][r] = v;
      float bvv = 0.f;
      if (!btrans) {
        int nn = lin & 63, kb = lin >> 6;
        if (k0 + kb < K && n0 + nn < Nn) bvv = Bm[(size_t)(k0 + kb) * Nn + (n0 + nn)];
        Bs[kb][nn] = bvv;
      } else {
        int kb = lin & 15, nn = lin >> 4;
        if (k0 + kb < K && n0 + nn < Nn) bvv = Bm[(size_t)(n0 + nn) * K + (k0 + kb)];
        Bs[kb][nn] = bvv;
      }
    }
    __syncthreads();
#pragma unroll
    for (int kk = 0; kk < 16; ++kk) {
      float4 a4 = *reinterpret_cast<const float4*>(&As[kk][ty << 2]);
      float4 b4 = *reinterpret_cast<const float4*>(&Bs[kk][tx << 2]);
      float av[4] = {a4.x, a4.y, a4.z, a4.w};
      float bv[4] = {b4.x, b4.y, b4.z, b4.w};
#pragma unroll
      for (int i2 = 0; i2 < 4; ++i2)
#pragma unroll
        for (int j2 = 0; j2 < 4; ++j2) acc[i2][j2] += av[i2] * bv[j2];
    }
    __syncthreads();
  }
#pragma unroll
  for (int i2 = 0; i2 < 4; ++i2) {
    int row = row0 + (ty << 2) + i2;
    if (row >= M) continue;
    bool zero = (rowmask != nullptr) && (rowmask[row] == 0);
#pragma unroll
    for (int j2 = 0; j2 < 4; ++j2) {
      int col = n0 + (tx << 2) + j2;
      if (col >= Nn) continue;
      float v = acc[i2][j2];
      if (bias) v += bias[col];
      if (dorelu) v = fmaxf(v, 0.f);
      if (zero) v = 0.f;
      C[(size_t)row * ldc + coloff + col] = v;
    }
  }
}

// ---------------------------------------------------------------------------
// attention: per batch item b; k/v rows are built on the fly as
// kproj[head]+kproj[NE+rel] (distributed projection trick).
// block = 256 threads: phase1 thread=(h,l), phase2 thread=(h,d)
// ---------------------------------------------------------------------------
__global__ __launch_bounds__(256) void attention_kernel(
    const float* __restrict__ qbuf, const float* __restrict__ kproj,
    const float* __restrict__ vproj, const int* __restrict__ head_seq,
    const int* __restrict__ rel_seq, const int* __restrict__ masks,
    float* __restrict__ ctx) {
  int b = blockIdx.x;
  int tid = threadIdx.x;
  __shared__ float qs[256];
  __shared__ float attns[8][33];
  __shared__ int hid[32], rid[32], ms[32];
  qs[tid] = qbuf[(size_t)b * 256 + tid];
  if (tid < 32) {
    hid[tid] = head_seq[b * LL + tid];
    rid[tid] = NE + rel_seq[b * LL + tid];
    ms[tid] = masks[b * LL + tid];
  }
  __syncthreads();
  int h = tid >> 5, l = tid & 31;
  const float* kp1 = kproj + (size_t)hid[l] * 256 + h * 32;
  const float* kp2 = kproj + (size_t)rid[l] * 256 + h * 32;
  float s = 0.f;
#pragma unroll
  for (int d2 = 0; d2 < 32; ++d2) s += qs[h * 32 + d2] * (kp1[d2] + kp2[d2]);
  s *= 0.17677669529663687f;  // 1/sqrt(32)
  s = ms[l] ? s : -1e9f;
  float m = s;
  for (int off = 16; off; off >>= 1) m = fmaxf(m, __shfl_xor(m, off, 32));
  float e = expf(s - m);
  float sum = e;
  for (int off = 16; off; off >>= 1) sum += __shfl_xor(sum, off, 32);
  attns[h][l] = e / sum;
  __syncthreads();
  int d = tid & 31;
  float c = 0.f;
  for (int l2 = 0; l2 < 32; ++l2) {
    float a = attns[h][l2];
    float v = vproj[(size_t)hid[l2] * 256 + h * 32 + d] + vproj[(size_t)rid[l2] * 256 + h * 32 + d];
    c += a * v;
  }
  ctx[(size_t)b * 256 + tid] = c;
}

// lem/rem kernel part: out[b, 0:300] = ent[ids[b], :]   (ld 600)
__global__ void gather_part_kernel(const float* __restrict__ ent, const int* __restrict__ ids,
                                   float* __restrict__ out) {
  int b = blockIdx.x;
  int t = threadIdx.x;
  if (t < DD) out[(size_t)b * 600 + t] = ent[(size_t)ids[b] * DD + t];
}

// normalized rows: outn[b,:] = rows[b,:] / max(||rows[b,:]||, 1e-8)   (ld 600)
__global__ __launch_bounds__(256) void rownorm_kernel(const float* __restrict__ rows,
                                                      float* __restrict__ outn) {
  int b = blockIdx.x;
  int t = threadIdx.x;
  const float* rp = rows + (size_t)b * 600;
  float s = 0.f;
  for (int c = t; c < 600; c += 256) { float v = rp[c]; s += v * v; }
  __shared__ float red[256];
  red[t] = s;
  __syncthreads();
  for (int off = 128; off; off >>= 1) {
    if (t < off) red[t] += red[t + off];
    __syncthreads();
  }
  __shared__ float inv;
  if (t == 0) inv = 1.f / fmaxf(sqrtf(red[0]), 1e-8f);
  __syncthreads();
  for (int c = t; c < 600; c += 256) outn[(size_t)b * 600 + c] = rp[c] * inv;
}

__global__ __launch_bounds__(256) void loss_reduce_kernel(const float* __restrict__ sim,
                                                          double* __restrict__ accum) {
  __shared__ float rn_[256], rp_[256];
  float negs = 0.f, poss = 0.f;
  for (int idx = blockIdx.x * blockDim.x + threadIdx.x; idx < BB * BB;
       idx += gridDim.x * blockDim.x) {
    int i = idx >> 11, j = idx & (BB - 1);
    float s = sim[idx];
    if (i == j) {
      negs += 0.2f;               // no_diag diagonal is 0 -> max(0, gamma2) = gamma2
      poss += fminf(s, 0.9f);
    } else {
      negs += fmaxf(s, 0.2f);
    }
  }
  rn_[threadIdx.x] = negs; rp_[threadIdx.x] = poss;
  __syncthreads();
  for (int off = 128; off; off >>= 1) {
    if (threadIdx.x < off) {
      rn_[threadIdx.x] += rn_[threadIdx.x + off];
      rp_[threadIdx.x] += rp_[threadIdx.x + off];
    }
    __syncthreads();
  }
  if (threadIdx.x == 0) {
    atomicAdd(&accum[0], (double)rn_[0]);
    atomicAdd(&accum[1], (double)rp_[0]);
  }
}

__global__ void finalize_kernel(const double* __restrict__ accum, float* __restrict__ out) {
  double neg = accum[0] / ((double)BB * (double)BB);
  double pos = accum[1] / (double)BB;
  out[0] = (float)(neg - 0.2 - pos + 0.9);
}

// ---------------------------------------------------------------------------
// host
// ---------------------------------------------------------------------------
static inline void launch_gemm(hipStream_t st, const float* A, const float* Bm,
                               const float* bias, float* C, int M, int Nn, int K, int ldc,
                               int coloff, const int* g1, int btrans, int dorelu,
                               const int* rowmask) {
  dim3 grid((Nn + 63) / 64, (M + 63) / 64);
  gemm64_kernel<<<grid, 256, 0, st>>>(A, Bm, bias, C, M, Nn, K, ldc, coloff, g1, btrans,
                                      dorelu, rowmask);
}

extern "C" void kernel_launch(void* const* d_in, const int* in_sizes, int n_in,
                              void* d_out, int out_size, void* d_ws, size_t ws_size,
                              hipStream_t stream) {
  const float* e_x    = (const float*)d_in[0];
  const float* r_x    = (const float*)d_in[1];
  const float* edge_w = (const float*)d_in[2];
  const float* Wrel   = (const float*)d_in[3];
  const float* brel   = (const float*)d_in[4];
  const float* W1     = (const float*)d_in[5];
  const float* b1     = (const float*)d_in[6];
  const float* W2     = (const float*)d_in[7];
  const float* b2     = (const float*)d_in[8];
  const float* Wprox  = (const float*)d_in[9];
  const float* bprox  = (const float*)d_in[10];
  const float* Wq     = (const float*)d_in[11];
  const float* Wk     = (const float*)d_in[12];
  const float* Wv     = (const float*)d_in[13];
  const float* Wo     = (const float*)d_in[14];
  const int* edge_src = (const int*)d_in[15];
  const int* edge_dst = (const int*)d_in[16];
  const int* l_ids    = (const int*)d_in[17];
  const int* r_ids    = (const int*)d_in[18];
  float* out = (float*)d_out;

  // ---- workspace layout (floats) ----
  float* F = (float*)d_ws;
  float* buf0   = F;                        // NTOT*DD = 15,120,000 (x / agg2 / kproj)
  float* buf1   = buf0 + (size_t)15120000;  // agg1 / h2 (persistent ent+rel features)
  float* buf2   = buf1 + (size_t)15120000;  // h1 / vproj
  float* emcatL = buf2 + (size_t)15120000;  // BB*600
  float* emcatR = emcatL + (size_t)1228800;
  float* qbuf   = emcatR + (size_t)1228800;  // BB*256
  float* ctxbuf = qbuf + (size_t)524288;     // BB*256
  float* lnbuf  = ctxbuf + (size_t)524288;   // BB*600
  float* rnbuf  = lnbuf + (size_t)1228800;
  float* simbuf = rnbuf + (size_t)1228800;   // BB*BB
  double* accum = (double*)(simbuf + (size_t)4194304);  // 2 doubles (8B aligned)
  int* row_ptr  = (int*)(accum + 2);         // NTOT+1
  int* cursor   = row_ptr + (NTOT + 1);      // NTOT
  int* counts   = cursor + NTOT;             // NTOT
  int* edge_idx = counts + NTOT;             // EE
  int* mask_norm= edge_idx + EE;             // 4 * BB*LL
  int* maskany  = mask_norm + 4 * BB * LL;   // 4 * BB
  int* flag     = maskany + 4 * BB;          // 1

  // ---- zero the bits that need it ----
  hipMemsetAsync(counts, 0, NTOT * sizeof(int), stream);
  hipMemsetAsync(maskany, 0, 4 * BB * sizeof(int), stream);
  hipMemsetAsync(flag, 0, sizeof(int), stream);
  hipMemsetAsync(accum, 0, 2 * sizeof(double), stream);

  // ---- x = [e_x ; r_x @ Wrel + brel] ----
  copy_f4_kernel<<<(3750000 + 255) / 256, 256, 0, stream>>>((const float4*)e_x, (float4*)buf0,
                                                            3750000);
  rel_proj_kernel<<<NR, 320, 0, stream>>>(r_x, Wrel, brel, buf0 + (size_t)NE * DD);

  // ---- CSR build ----
  hist_kernel<<<(EE + 255) / 256, 256, 0, stream>>>(edge_dst, counts);
  scan_kernel<<<1, 1024, 0, stream>>>(counts, row_ptr, cursor);
  scatter_kernel<<<(EE + 255) / 256, 256, 0, stream>>>(edge_dst, cursor, edge_idx);

  // ---- mask normalization ----
  detect_mask_kernel<<<256, 256, 0, stream>>>((const unsigned*)d_in[21], (const unsigned*)d_in[24],
                                              (const unsigned*)d_in[27], (const unsigned*)d_in[30],
                                              flag);
  for (int mi = 0; mi < 4; ++mi) {
    norm_mask_kernel<<<(BB * LL + 255) / 256, 256, 0, stream>>>(
        d_in[21 + mi * 3], mask_norm + (size_t)mi * BB * LL, maskany + mi * BB, flag);
  }

  // ---- GCN ----
  aggregate_kernel<<<NTOT, 320, 0, stream>>>(buf0, buf1, row_ptr, edge_idx, edge_src, edge_w);
  launch_gemm(stream, buf1, W1, b1, buf2, NTOT, DD, DD, DD, 0, nullptr, 0, 1, nullptr);  // h1
  aggregate_kernel<<<NTOT, 320, 0, stream>>>(buf2, buf0, row_ptr, edge_idx, edge_src, edge_w);
  launch_gemm(stream, buf0, W2, b2, buf1, NTOT, DD, DD, DD, 0, nullptr, 0, 0, nullptr);  // h2

  // buf1 now holds h2 = [gcn_ex ; gcn_rx] and persists. buf0/buf2 become k/v proj.
  // ---- encoders: tok@W = proj[head] + proj[NE+rel] ----
  for (int dir = 0; dir < 2; ++dir) {
    launch_gemm(stream, buf1, Wk + (size_t)dir * DD * HD, nullptr, buf0, NTOT, HD, DD, HD, 0,
                nullptr, 0, 0, nullptr);  // kproj
    launch_gemm(stream, buf1, Wv + (size_t)dir * DD * HD, nullptr, buf2, NTOT, HD, DD, HD, 0,
                nullptr, 0, 0, nullptr);  // vproj
    for (int side = 0; side < 2; ++side) {
      const int* ids = side ? r_ids : l_ids;
      int mi = side * 2 + dir;  // l_in=0, l_out=1, r_in=2, r_out=3
      const int* rel_seq  = (const int*)d_in[19 + side * 6 + dir * 3];
      const int* head_seq = (const int*)d_in[20 + side * 6 + dir * 3];
      launch_gemm(stream, buf1, Wq + (size_t)dir * DD * HD, nullptr, qbuf, BB, HD, DD, HD, 0,
                  ids, 0, 0, nullptr);  // q = ent_f[ids] @ Wq
      attention_kernel<<<BB, 256, 0, stream>>>(qbuf, buf0, buf2, head_seq, rel_seq,
                                               mask_norm + (size_t)mi * BB * LL, ctxbuf);
      float* emc = side ? emcatR : emcatL;
      launch_gemm(stream, ctxbuf, Wo + (size_t)dir * HD * DD, nullptr, emc, BB, DD, HD, 600,
                  dir * DD, nullptr, 0, 0, maskany + mi * BB);  // out = ctx @ Wo, masked rows -> 0
    }
  }

  // ---- proximity + assemble lem/rem (d_out[0]=loss, then lem, then rem) ----
  float* lem = out + 1;
  float* rem = out + 1 + (size_t)BB * 600;
  launch_gemm(stream, emcatL, Wprox, bprox, lem, BB, DD, 600, 600, DD, nullptr, 0, 0, nullptr);
  launch_gemm(stream, emcatR, Wprox, bprox, rem, BB, DD, 600, 600, DD, nullptr, 0, 0, nullptr);
  gather_part_kernel<<<BB, 320, 0, stream>>>(buf1, l_ids, lem);
  gather_part_kernel<<<BB, 320, 0, stream>>>(buf1, r_ids, rem);

  // ---- cosine similarity + loss ----
  rownorm_kernel<<<BB, 256, 0, stream>>>(lem, lnbuf);
  rownorm_kernel<<<BB, 256, 0, stream>>>(rem, rnbuf);
  launch_gemm(stream, lnbuf, rnbuf, nullptr, simbuf, BB, BB, 600, BB, 0, nullptr, 1, 0, nullptr);
  loss_reduce_kernel<<<2048, 256, 0, stream>>>(simbuf, accum);
  finalize_kernel<<<1, 1, 0, stream>>>(accum, out);
}

// Round 3
// 1631.047 us; speedup vs baseline: 2.2505x; 2.2505x over previous
//
#include <hip/hip_runtime.h>
#include <cstdint>
#include <cstddef>

typedef unsigned short u16;
typedef __attribute__((ext_vector_type(8))) short short8;
typedef __attribute__((ext_vector_type(4))) float f32x4;

#define NE 50000
#define NR 400
#define DD 300
#define NTOT 50400
#define EE 800000
#define BB 2048
#define LL 32
#define HD 256
#define KP1 320
#define KP2 608

// round-to-nearest-even split of fp32 into bf16 hi + bf16 lo
__device__ inline void split2(float x, u16& hi, u16& lo) {
  unsigned u = __float_as_uint(x);
  unsigned hb = (u + 0x7fffu + ((u >> 16) & 1u)) >> 16;
  hi = (u16)hb;
  float hf = __uint_as_float(hb << 16);
  float l = x - hf;
  unsigned ul = __float_as_uint(l);
  lo = (u16)((ul + 0x7fffu + ((ul >> 16) & 1u)) >> 16);
}
__device__ inline float bf2f(u16 h) { return __uint_as_float(((unsigned)h) << 16); }

// ---------------------------------------------------------------------------
__global__ void copy_f4_kernel(const float4* __restrict__ src, float4* __restrict__ dst, int n4) {
  int i = blockIdx.x * blockDim.x + threadIdx.x;
  if (i < n4) dst[i] = src[i];
}

__global__ void rel_proj_kernel(const float* __restrict__ r_x, const float* __restrict__ Wrel,
                                const float* __restrict__ brel, float* __restrict__ out) {
  int row = blockIdx.x;
  int c = threadIdx.x;
  if (c >= DD) return;
  float acc = brel[c];
  const float* rr = r_x + (size_t)row * (2 * DD);
  for (int k = 0; k < 2 * DD; ++k) acc += rr[k] * Wrel[(size_t)k * DD + c];
  out[(size_t)row * DD + c] = acc;
}

__global__ void hist_kernel(const int* __restrict__ dst, int* __restrict__ counts) {
  int e = blockIdx.x * blockDim.x + threadIdx.x;
  if (e < EE) atomicAdd(&counts[dst[e]], 1);
}

__global__ __launch_bounds__(1024) void scan_kernel(const int* __restrict__ counts,
                                                    int* __restrict__ row_ptr,
                                                    int* __restrict__ cursor) {
  __shared__ int sums[1024];
  const int n = NTOT;
  int t = threadIdx.x;
  const int chunk = (n + 1023) / 1024;
  int begin = t * chunk;
  int end = begin + chunk; if (end > n) end = n;
  int s = 0;
  for (int i = begin; i < end; ++i) s += counts[i];
  sums[t] = s;
  __syncthreads();
  for (int off = 1; off < 1024; off <<= 1) {
    int v = (t >= off) ? sums[t - off] : 0;
    __syncthreads();
    sums[t] += v;
    __syncthreads();
  }
  int run = sums[t] - s;
  for (int i = begin; i < end; ++i) {
    row_ptr[i] = run; cursor[i] = run;
    run += counts[i];
  }
  if (t == 1023) row_ptr[n] = sums[1023];
}

// scatter: write src & w already sorted by dst (kills one indirection in aggregate)
__global__ void scatter_kernel(const int* __restrict__ dst, const int* __restrict__ src,
                               const float* __restrict__ w, int* __restrict__ cursor,
                               int* __restrict__ src_s, float* __restrict__ w_s) {
  int e = blockIdx.x * blockDim.x + threadIdx.x;
  if (e < EE) {
    int pos = atomicAdd(&cursor[dst[e]], 1);
    src_s[pos] = src[e];
    w_s[pos] = w[e];
  }
}

__global__ void detect_mask_kernel(const unsigned* __restrict__ m0, const unsigned* __restrict__ m1,
                                   const unsigned* __restrict__ m2, const unsigned* __restrict__ m3,
                                   int* __restrict__ flag) {
  int idx = blockIdx.x * blockDim.x + threadIdx.x;
  const int wp = BB * LL / 4;
  if (idx >= 4 * wp) return;
  const unsigned* p = idx < wp ? m0 : idx < 2 * wp ? m1 : idx < 3 * wp ? m2 : m3;
  if (p[idx % wp] > 1u) atomicOr(flag, 1);
}

__global__ void norm_mask_kernel(const void* __restrict__ raw, int* __restrict__ outm,
                                 int* __restrict__ many, const int* __restrict__ flag) {
  int idx = blockIdx.x * blockDim.x + threadIdx.x;
  if (idx >= BB * LL) return;
  int v = (*flag) ? (int)((const unsigned char*)raw)[idx] : ((const int*)raw)[idx];
  v = v ? 1 : 0;
  outm[idx] = v;
  if (v) atomicOr(&many[idx >> 5], 1);
}

// aggregate with 4-edge unroll (4x MLP); writes split bf16 hi/lo at ld=KP1
__global__ __launch_bounds__(320) void aggregate_kernel(
    const float* __restrict__ feat, u16* __restrict__ outhi, u16* __restrict__ outlo,
    const int* __restrict__ row_ptr, const int* __restrict__ srcs, const float* __restrict__ ws) {
  int d = blockIdx.x;
  int f = threadIdx.x;
  if (f >= DD) return;
  int beg = row_ptr[d], end = row_ptr[d + 1];
  float acc = 0.f;
  int e = beg;
  for (; e + 4 <= end; e += 4) {
    int s0 = srcs[e], s1 = srcs[e + 1], s2 = srcs[e + 2], s3 = srcs[e + 3];
    float w0 = ws[e], w1 = ws[e + 1], w2 = ws[e + 2], w3 = ws[e + 3];
    float v0 = feat[(size_t)s0 * DD + f];
    float v1 = feat[(size_t)s1 * DD + f];
    float v2 = feat[(size_t)s2 * DD + f];
    float v3 = feat[(size_t)s3 * DD + f];
    acc += w0 * v0 + w1 * v1 + w2 * v2 + w3 * v3;
  }
  for (; e < end; ++e) acc += ws[e] * feat[(size_t)srcs[e] * DD + f];
  u16 hi, lo; split2(acc, hi, lo);
  outhi[(size_t)d * KP1 + f] = hi;
  outlo[(size_t)d * KP1 + f] = lo;
}

// zero the K-pad columns [c0, ld) of a hi/lo pair
__global__ void pad_zero_kernel(u16* __restrict__ hi, u16* __restrict__ lo, int rows, int ld, int c0) {
  int pw = ld - c0;
  int idx = blockIdx.x * blockDim.x + threadIdx.x;
  if (idx >= rows * pw) return;
  int r = idx / pw, c = c0 + idx % pw;
  hi[(size_t)r * ld + c] = 0;
  lo[(size_t)r * ld + c] = 0;
}

// weight transpose + split: in [Kreal x Nn] fp32 -> out [Nn x Kpad] bf16 hi/lo, z matrices
__global__ void transpose_split_kernel(const float* __restrict__ in, int insz,
                                       u16* __restrict__ outhi, u16* __restrict__ outlo, int outsz,
                                       int Kreal, int Nn, int Kpad) {
  int z = blockIdx.y;
  int idx = blockIdx.x * blockDim.x + threadIdx.x;
  if (idx >= Nn * Kpad) return;
  int n = idx / Kpad, k = idx % Kpad;
  float v = (k < Kreal) ? in[(size_t)z * insz + (size_t)k * Nn + n] : 0.f;
  u16 hi, lo; split2(v, hi, lo);
  outhi[(size_t)z * outsz + idx] = hi;
  outlo[(size_t)z * outsz + idx] = lo;
}

// ---------------------------------------------------------------------------
// split-bf16 MFMA GEMM: C = gather(A) @ B^T via 3 passes (ah*bh + ah*bl + al*bh)
// A stored [M x lda] bf16 hi/lo (K-contig); B stored [Nn x ldb] bf16 hi/lo (K-contig = B^T).
// 128x128 tile, 256 threads (4 waves, 2x2 of 64x64), 16x16x32 MFMA.
// LDS XOR-swizzle: chunk' = chunk ^ ((row>>1)&3) -> conflict-free-equivalent frag reads.
// ---------------------------------------------------------------------------
__global__ __launch_bounds__(256, 2) void mfma_gemm_kernel(
    const u16* __restrict__ Ahi, const u16* __restrict__ Alo, int lda,
    const u16* __restrict__ Bhi, const u16* __restrict__ Blo, int ldb,
    int M, int Nn, int K, const int* __restrict__ g1,
    float* __restrict__ C, int ldc, int coloff,
    const float* __restrict__ bias, int dorelu, const int* __restrict__ rowmask,
    u16* __restrict__ Chi, u16* __restrict__ Clo, int ldc16) {
  __shared__ int4 sAh[512], sAl[512], sBh[512], sBl[512];
  const int tid = threadIdx.x;
  const int row0 = blockIdx.y * 128, col0 = blockIdx.x * 128;
  const int wave = tid >> 6, lane = tid & 63;
  const int wrow = (wave >> 1) * 64, wcol = (wave & 1) * 64;
  const int m16 = lane & 15, quad = lane >> 4;

  const int sr = tid >> 2, sc = tid & 3;
  const u16* pah[2]; const u16* pal[2]; bool va[2];
  const u16* pbh[2]; const u16* pbl[2]; bool vb[2];
  int sidx[2];
#pragma unroll
  for (int i = 0; i < 2; ++i) {
    int r = sr + i * 64;
    sidx[i] = r * 4 + (sc ^ ((r >> 1) & 3));
    int grow = row0 + r;
    va[i] = grow < M;
    int ar = va[i] ? (g1 ? g1[grow] : grow) : 0;
    pah[i] = Ahi + (size_t)ar * lda + sc * 8;
    pal[i] = Alo + (size_t)ar * lda + sc * 8;
    int gn = col0 + r;
    vb[i] = gn < Nn;
    int br = vb[i] ? gn : 0;
    pbh[i] = Bhi + (size_t)br * ldb + sc * 8;
    pbl[i] = Blo + (size_t)br * ldb + sc * 8;
  }
  int idxA[4], idxB[4];
#pragma unroll
  for (int f = 0; f < 4; ++f) {
    int r = wrow + f * 16 + m16;
    idxA[f] = r * 4 + (quad ^ ((r >> 1) & 3));
    int n = wcol + f * 16 + m16;
    idxB[f] = n * 4 + (quad ^ ((n >> 1) & 3));
  }
  f32x4 acc[4][4];
#pragma unroll
  for (int i = 0; i < 4; ++i)
#pragma unroll
    for (int j = 0; j < 4; ++j) acc[i][j] = (f32x4){0.f, 0.f, 0.f, 0.f};

  const int4 z4 = {0, 0, 0, 0};
  for (int k0 = 0; k0 < K; k0 += 32) {
#pragma unroll
    for (int i = 0; i < 2; ++i) {
      int4 vh = z4, vl = z4, wh = z4, wl = z4;
      if (va[i]) { vh = *(const int4*)(pah[i] + k0); vl = *(const int4*)(pal[i] + k0); }
      if (vb[i]) { wh = *(const int4*)(pbh[i] + k0); wl = *(const int4*)(pbl[i] + k0); }
      sAh[sidx[i]] = vh; sAl[sidx[i]] = vl;
      sBh[sidx[i]] = wh; sBl[sidx[i]] = wl;
    }
    __syncthreads();
    short8 ah[4], al[4], bh[4], bl[4];
#pragma unroll
    for (int f = 0; f < 4; ++f) {
      ah[f] = *(const short8*)&sAh[idxA[f]];
      al[f] = *(const short8*)&sAl[idxA[f]];
      bh[f] = *(const short8*)&sBh[idxB[f]];
      bl[f] = *(const short8*)&sBl[idxB[f]];
    }
#pragma unroll
    for (int i = 0; i < 4; ++i)
#pragma unroll
      for (int j = 0; j < 4; ++j)
        acc[i][j] = __builtin_amdgcn_mfma_f32_16x16x32_bf16(ah[i], bh[j], acc[i][j], 0, 0, 0);
#pragma unroll
    for (int i = 0; i < 4; ++i)
#pragma unroll
      for (int j = 0; j < 4; ++j)
        acc[i][j] = __builtin_amdgcn_mfma_f32_16x16x32_bf16(ah[i], bl[j], acc[i][j], 0, 0, 0);
#pragma unroll
    for (int i = 0; i < 4; ++i)
#pragma unroll
      for (int j = 0; j < 4; ++j)
        acc[i][j] = __builtin_amdgcn_mfma_f32_16x16x32_bf16(al[i], bh[j], acc[i][j], 0, 0, 0);
    __syncthreads();
  }
  // epilogue: C/D map col=lane&15, row=quad*4+reg  [m89/m91-verified]
#pragma unroll
  for (int i = 0; i < 4; ++i) {
#pragma unroll
    for (int reg = 0; reg < 4; ++reg) {
      int row = row0 + wrow + i * 16 + quad * 4 + reg;
      if (row >= M) continue;
      bool zero = (rowmask != nullptr) && (rowmask[row] == 0);
#pragma unroll
      for (int j = 0; j < 4; ++j) {
        int col = col0 + wcol + j * 16 + m16;
        if (col >= Nn) continue;
        float v = acc[i][j][reg];
        if (bias) v += bias[col];
        if (dorelu) v = fmaxf(v, 0.f);
        if (zero) v = 0.f;
        if (C) C[(size_t)row * ldc + coloff + col] = v;
        if (Chi) {
          u16 hb, lb; split2(v, hb, lb);
          Chi[(size_t)row * ldc16 + coloff + col] = hb;
          Clo[(size_t)row * ldc16 + coloff + col] = lb;
        }
      }
    }
  }
}

// ---------------------------------------------------------------------------
__global__ __launch_bounds__(256) void attention_kernel(
    const float* __restrict__ qbuf, const float* __restrict__ kproj,
    const float* __restrict__ vproj, const int* __restrict__ head_seq,
    const int* __restrict__ rel_seq, const int* __restrict__ masks,
    u16* __restrict__ ctxhi, u16* __restrict__ ctxlo) {
  int b = blockIdx.x;
  int tid = threadIdx.x;
  __shared__ float qs[256];
  __shared__ float attns[8][33];
  __shared__ int hid[32], rid[32], ms[32];
  qs[tid] = qbuf[(size_t)b * 256 + tid];
  if (tid < 32) {
    hid[tid] = head_seq[b * LL + tid];
    rid[tid] = NE + rel_seq[b * LL + tid];
    ms[tid] = masks[b * LL + tid];
  }
  __syncthreads();
  int h = tid >> 5, l = tid & 31;
  const float* kp1 = kproj + (size_t)hid[l] * 256 + h * 32;
  const float* kp2 = kproj + (size_t)rid[l] * 256 + h * 32;
  float s = 0.f;
#pragma unroll
  for (int d2 = 0; d2 < 32; ++d2) s += qs[h * 32 + d2] * (kp1[d2] + kp2[d2]);
  s *= 0.17677669529663687f;
  s = ms[l] ? s : -1e9f;
  float m = s;
  for (int off = 16; off; off >>= 1) m = fmaxf(m, __shfl_xor(m, off, 32));
  float e = expf(s - m);
  float sum = e;
  for (int off = 16; off; off >>= 1) sum += __shfl_xor(sum, off, 32);
  attns[h][l] = e / sum;
  __syncthreads();
  int d = tid & 31;
  float c = 0.f;
  for (int l2 = 0; l2 < 32; ++l2) {
    float a = attns[h][l2];
    float v = vproj[(size_t)hid[l2] * 256 + h * 32 + d] + vproj[(size_t)rid[l2] * 256 + h * 32 + d];
    c += a * v;
  }
  u16 hb, lb; split2(c, hb, lb);
  ctxhi[(size_t)b * 256 + tid] = hb;
  ctxlo[(size_t)b * 256 + tid] = lb;
}

// out[b, 0:300] = h2[ids[b], :] reconstructed from hi/lo (ld 600)
__global__ void gather_part_kernel(const u16* __restrict__ enthi, const u16* __restrict__ entlo,
                                   const int* __restrict__ ids, float* __restrict__ out) {
  int b = blockIdx.x;
  int t = threadIdx.x;
  if (t < DD) {
    size_t o = (size_t)ids[b] * KP1 + t;
    out[(size_t)b * 600 + t] = bf2f(enthi[o]) + bf2f(entlo[o]);
  }
}

// row-normalize (ld 600 fp32 in) -> split bf16 hi/lo at ld 608 with zero pads
__global__ __launch_bounds__(256) void rownorm_kernel(const float* __restrict__ rows,
                                                      u16* __restrict__ outhi,
                                                      u16* __restrict__ outlo) {
  int b = blockIdx.x;
  int t = threadIdx.x;
  const float* rp = rows + (size_t)b * 600;
  float s = 0.f;
  for (int c = t; c < 600; c += 256) { float v = rp[c]; s += v * v; }
  __shared__ float red[256];
  red[t] = s;
  __syncthreads();
  for (int off = 128; off; off >>= 1) {
    if (t < off) red[t] += red[t + off];
    __syncthreads();
  }
  __shared__ float inv;
  if (t == 0) inv = 1.f / fmaxf(sqrtf(red[0]), 1e-8f);
  __syncthreads();
  for (int c = t; c < KP2; c += 256) {
    float v = (c < 600) ? rp[c] * inv : 0.f;
    u16 hb, lb; split2(v, hb, lb);
    outhi[(size_t)b * KP2 + c] = hb;
    outlo[(size_t)b * KP2 + c] = lb;
  }
}

__global__ __launch_bounds__(256) void loss_reduce_kernel(const float* __restrict__ sim,
                                                          double* __restrict__ accum) {
  __shared__ float rn_[256], rp_[256];
  float negs = 0.f, poss = 0.f;
  for (int idx = blockIdx.x * blockDim.x + threadIdx.x; idx < BB * BB;
       idx += gridDim.x * blockDim.x) {
    int i = idx >> 11, j = idx & (BB - 1);
    float s = sim[idx];
    if (i == j) {
      negs += 0.2f;
      poss += fminf(s, 0.9f);
    } else {
      negs += fmaxf(s, 0.2f);
    }
  }
  rn_[threadIdx.x] = negs; rp_[threadIdx.x] = poss;
  __syncthreads();
  for (int off = 128; off; off >>= 1) {
    if (threadIdx.x < off) {
      rn_[threadIdx.x] += rn_[threadIdx.x + off];
      rp_[threadIdx.x] += rp_[threadIdx.x + off];
    }
    __syncthreads();
  }
  if (threadIdx.x == 0) {
    atomicAdd(&accum[0], (double)rn_[0]);
    atomicAdd(&accum[1], (double)rp_[0]);
  }
}

__global__ void finalize_kernel(const double* __restrict__ accum, float* __restrict__ out) {
  double neg = accum[0] / ((double)BB * (double)BB);
  double pos = accum[1] / (double)BB;
  out[0] = (float)(neg - 0.2 - pos + 0.9);
}

// ---------------------------------------------------------------------------
static inline void launch_mfma(hipStream_t st, const u16* Ahi, const u16* Alo, int lda,
                               const u16* Bhi, const u16* Blo, int ldb, int M, int Nn, int K,
                               const int* g1, float* C, int ldc, int coloff, const float* bias,
                               int dorelu, const int* rowmask, u16* Chi, u16* Clo, int ldc16) {
  dim3 grid((Nn + 127) / 128, (M + 127) / 128);
  mfma_gemm_kernel<<<grid, 256, 0, st>>>(Ahi, Alo, lda, Bhi, Blo, ldb, M, Nn, K, g1, C, ldc,
                                         coloff, bias, dorelu, rowmask, Chi, Clo, ldc16);
}

extern "C" void kernel_launch(void* const* d_in, const int* in_sizes, int n_in,
                              void* d_out, int out_size, void* d_ws, size_t ws_size,
                              hipStream_t stream) {
  const float* e_x    = (const float*)d_in[0];
  const float* r_x    = (const float*)d_in[1];
  const float* edge_w = (const float*)d_in[2];
  const float* Wrel   = (const float*)d_in[3];
  const float* brel   = (const float*)d_in[4];
  const float* W1     = (const float*)d_in[5];
  const float* b1     = (const float*)d_in[6];
  const float* W2     = (const float*)d_in[7];
  const float* b2     = (const float*)d_in[8];
  const float* Wprox  = (const float*)d_in[9];
  const float* bprox  = (const float*)d_in[10];
  const float* Wq     = (const float*)d_in[11];
  const float* Wk     = (const float*)d_in[12];
  const float* Wv     = (const float*)d_in[13];
  const float* Wo     = (const float*)d_in[14];
  const int* edge_src = (const int*)d_in[15];
  const int* edge_dst = (const int*)d_in[16];
  const int* l_ids    = (const int*)d_in[17];
  const int* r_ids    = (const int*)d_in[18];
  float* out = (float*)d_out;

  // ---- workspace ----
  char* base = (char*)d_ws;
  size_t off = 0;
  auto nxt = [&](size_t bytes) -> char* {
    char* p = base + off;
    off += (bytes + 63) & ~(size_t)63;
    return p;
  };
  char* R0 = nxt(64512000);   // x (fp32 NTOT*300) then h2 hi/lo (NTOT*320 each)
  char* R1 = nxt(64512000);   // agg hi/lo then vbuf fp32
  char* R2 = nxt(60480000);   // h1 fp32 then kbuf fp32 then simbuf
  float* qbuf = (float*)nxt(2097152);
  u16* ctxhi = (u16*)nxt(1048576);
  u16* ctxlo = (u16*)nxt(1048576);
  u16* emLhi = (u16*)nxt(2490368);
  u16* emLlo = (u16*)nxt(2490368);
  u16* emRhi = (u16*)nxt(2490368);
  u16* emRlo = (u16*)nxt(2490368);
  u16* lnhi  = (u16*)nxt(2490368);
  u16* lnlo  = (u16*)nxt(2490368);
  u16* rnhi  = (u16*)nxt(2490368);
  u16* rnlo  = (u16*)nxt(2490368);
  u16* qkvhi = (u16*)nxt(983040);   // 6 x [256 x 320]
  u16* qkvlo = (u16*)nxt(983040);
  u16* w12hi = (u16*)nxt(384000);   // 2 x [300 x 320]
  u16* w12lo = (u16*)nxt(384000);
  u16* wohi  = (u16*)nxt(307200);   // 2 x [300 x 256]
  u16* wolo  = (u16*)nxt(307200);
  u16* wpxhi = (u16*)nxt(364800);   // [300 x 608]
  u16* wpxlo = (u16*)nxt(364800);
  double* accum = (double*)nxt(16);
  int* row_ptr  = (int*)nxt(4 * (NTOT + 1));
  int* cursor   = (int*)nxt(4 * NTOT);
  int* counts   = (int*)nxt(4 * NTOT);
  int* src_s    = (int*)nxt(4 * EE);
  float* w_s    = (float*)nxt(4 * EE);
  int* mask_norm = (int*)nxt(4 * 4 * BB * LL);
  int* maskany   = (int*)nxt(4 * 4 * BB);
  int* flag      = (int*)nxt(64);

  float* xbuf = (float*)R0;
  u16* h2hi = (u16*)R0;  u16* h2lo = h2hi + 16128000;
  u16* agghi = (u16*)R1; u16* agglo = agghi + 16128000;
  float* vbuf = (float*)R1;
  float* h1 = (float*)R2;
  float* kbuf = (float*)R2;
  float* simbuf = (float*)R2;

  hipMemsetAsync(counts, 0, NTOT * sizeof(int), stream);
  hipMemsetAsync(maskany, 0, 4 * BB * sizeof(int), stream);
  hipMemsetAsync(flag, 0, sizeof(int), stream);
  hipMemsetAsync(accum, 0, 2 * sizeof(double), stream);

  // x = [e_x ; r_x @ Wrel + brel]
  copy_f4_kernel<<<(3750000 + 255) / 256, 256, 0, stream>>>((const float4*)e_x, (float4*)xbuf,
                                                            3750000);
  rel_proj_kernel<<<NR, 320, 0, stream>>>(r_x, Wrel, brel, xbuf + (size_t)NE * DD);

  // CSR (sorted src/w)
  hist_kernel<<<(EE + 255) / 256, 256, 0, stream>>>(edge_dst, counts);
  scan_kernel<<<1, 1024, 0, stream>>>(counts, row_ptr, cursor);
  scatter_kernel<<<(EE + 255) / 256, 256, 0, stream>>>(edge_dst, edge_src, edge_w, cursor, src_s,
                                                       w_s);

  // masks
  detect_mask_kernel<<<256, 256, 0, stream>>>((const unsigned*)d_in[21], (const unsigned*)d_in[24],
                                              (const unsigned*)d_in[27], (const unsigned*)d_in[30],
                                              flag);
  for (int mi = 0; mi < 4; ++mi)
    norm_mask_kernel<<<(BB * LL + 255) / 256, 256, 0, stream>>>(
        d_in[21 + mi * 3], mask_norm + (size_t)mi * BB * LL, maskany + mi * BB, flag);

  // weight transposes (fp32 [K x N] -> bf16 hi/lo [N x Kpad])
  transpose_split_kernel<<<dim3((256 * KP1 + 255) / 256, 2), 256, 0, stream>>>(
      Wq, 300 * 256, qkvhi + 0 * 81920, qkvlo + 0 * 81920, 81920, 300, 256, KP1);
  transpose_split_kernel<<<dim3((256 * KP1 + 255) / 256, 2), 256, 0, stream>>>(
      Wk, 300 * 256, qkvhi + 2 * 81920, qkvlo + 2 * 81920, 81920, 300, 256, KP1);
  transpose_split_kernel<<<dim3((256 * KP1 + 255) / 256, 2), 256, 0, stream>>>(
      Wv, 300 * 256, qkvhi + 4 * 81920, qkvlo + 4 * 81920, 81920, 300, 256, KP1);
  transpose_split_kernel<<<dim3((300 * KP1 + 255) / 256, 1), 256, 0, stream>>>(
      W1, 0, w12hi, w12lo, 96000, 300, 300, KP1);
  transpose_split_kernel<<<dim3((300 * KP1 + 255) / 256, 1), 256, 0, stream>>>(
      W2, 0, w12hi + 96000, w12lo + 96000, 96000, 300, 300, KP1);
  transpose_split_kernel<<<dim3((300 * 256 + 255) / 256, 2), 256, 0, stream>>>(
      Wo, 256 * 300, wohi, wolo, 76800, 256, 300, 256);
  transpose_split_kernel<<<dim3((300 * KP2 + 255) / 256, 1), 256, 0, stream>>>(
      Wprox, 0, wpxhi, wpxlo, 182400, 600, 300, KP2);

  // K-pad zeroing
  pad_zero_kernel<<<(NTOT * 20 + 255) / 256, 256, 0, stream>>>(agghi, agglo, NTOT, KP1, 300);
  pad_zero_kernel<<<(BB * 8 + 255) / 256, 256, 0, stream>>>(emLhi, emLlo, BB, KP2, 600);
  pad_zero_kernel<<<(BB * 8 + 255) / 256, 256, 0, stream>>>(emRhi, emRlo, BB, KP2, 600);

  // GCN
  aggregate_kernel<<<NTOT, 320, 0, stream>>>(xbuf, agghi, agglo, row_ptr, src_s, w_s);
  launch_mfma(stream, agghi, agglo, KP1, w12hi, w12lo, KP1, NTOT, 300, KP1, nullptr, h1, 300, 0,
              b1, 1, nullptr, nullptr, nullptr, 0);
  aggregate_kernel<<<NTOT, 320, 0, stream>>>(h1, agghi, agglo, row_ptr, src_s, w_s);
  pad_zero_kernel<<<(NTOT * 20 + 255) / 256, 256, 0, stream>>>(h2hi, h2lo, NTOT, KP1, 300);
  launch_mfma(stream, agghi, agglo, KP1, w12hi + 96000, w12lo + 96000, KP1, NTOT, 300, KP1,
              nullptr, nullptr, 0, 0, b2, 0, nullptr, h2hi, h2lo, KP1);

  // encoders
  for (int dir = 0; dir < 2; ++dir) {
    launch_mfma(stream, h2hi, h2lo, KP1, qkvhi + (2 + dir) * 81920, qkvlo + (2 + dir) * 81920,
                KP1, NTOT, 256, KP1, nullptr, kbuf, 256, 0, nullptr, 0, nullptr, nullptr, nullptr,
                0);
    launch_mfma(stream, h2hi, h2lo, KP1, qkvhi + (4 + dir) * 81920, qkvlo + (4 + dir) * 81920,
                KP1, NTOT, 256, KP1, nullptr, vbuf, 256, 0, nullptr, 0, nullptr, nullptr, nullptr,
                0);
    for (int side = 0; side < 2; ++side) {
      const int* ids = side ? r_ids : l_ids;
      int mi = side * 2 + dir;
      const int* rel_seq  = (const int*)d_in[19 + side * 6 + dir * 3];
      const int* head_seq = (const int*)d_in[20 + side * 6 + dir * 3];
      launch_mfma(stream, h2hi, h2lo, KP1, qkvhi + dir * 81920, qkvlo + dir * 81920, KP1, BB, 256,
                  KP1, ids, qbuf, 256, 0, nullptr, 0, nullptr, nullptr, nullptr, 0);
      attention_kernel<<<BB, 256, 0, stream>>>(qbuf, kbuf, vbuf, head_seq, rel_seq,
                                               mask_norm + (size_t)mi * BB * LL, ctxhi, ctxlo);
      // FIX (R2 bug): out_em (dir=1) must land in emcat cols 300..599 -> coloff = dir*300
      launch_mfma(stream, ctxhi, ctxlo, 256, wohi + dir * 76800, wolo + dir * 76800, 256, BB, 300,
                  256, nullptr, nullptr, 0, dir * 300, nullptr, 0, maskany + mi * BB,
                  side ? emRhi : emLhi, side ? emRlo : emLlo, KP2);
    }
  }

  // proximity + lem/rem assembly (d_out: [loss, lem, rem])
  float* lem = out + 1;
  float* rem = out + 1 + (size_t)BB * 600;
  launch_mfma(stream, emLhi, emLlo, KP2, wpxhi, wpxlo, KP2, BB, 300, KP2, nullptr, lem, 600, 300,
              bprox, 0, nullptr, nullptr, nullptr, 0);
  launch_mfma(stream, emRhi, emRlo, KP2, wpxhi, wpxlo, KP2, BB, 300, KP2, nullptr, rem, 600, 300,
              bprox, 0, nullptr, nullptr, nullptr, 0);
  gather_part_kernel<<<BB, 320, 0, stream>>>(h2hi, h2lo, l_ids, lem);
  gather_part_kernel<<<BB, 320, 0, stream>>>(h2hi, h2lo, r_ids, rem);

  // cosine similarity + loss
  rownorm_kernel<<<BB, 256, 0, stream>>>(lem, lnhi, lnlo);
  rownorm_kernel<<<BB, 256, 0, stream>>>(rem, rnhi, rnlo);
  launch_mfma(stream, lnhi, lnlo, KP2, rnhi, rnlo, KP2, BB, BB, KP2, nullptr, simbuf, BB, 0,
              nullptr, 0, nullptr, nullptr, nullptr, 0);
  loss_reduce_kernel<<<2048, 256, 0, stream>>>(simbuf, accum);
  finalize_kernel<<<1, 1, 0, stream>>>(accum, out);
}

// Round 4
// 1452.774 us; speedup vs baseline: 2.5267x; 1.1227x over previous
//
#include <hip/hip_runtime.h>
#include <cstdint>
#include <cstddef>

typedef unsigned short u16;
typedef __attribute__((ext_vector_type(8))) short short8;
typedef __attribute__((ext_vector_type(4))) float f32x4;

#define NE 50000
#define NR 400
#define DD 300
#define NTOT 50400
#define EE 800000
#define BB 2048
#define LL 32
#define HD 256
#define KP1 320
#define KP2 608

// round-to-nearest-even split of fp32 into bf16 hi + bf16 lo
__device__ inline void split2(float x, u16& hi, u16& lo) {
  unsigned u = __float_as_uint(x);
  unsigned hb = (u + 0x7fffu + ((u >> 16) & 1u)) >> 16;
  hi = (u16)hb;
  float hf = __uint_as_float(hb << 16);
  float l = x - hf;
  unsigned ul = __float_as_uint(l);
  lo = (u16)((ul + 0x7fffu + ((ul >> 16) & 1u)) >> 16);
}
__device__ inline float bf2f(u16 h) { return __uint_as_float(((unsigned)h) << 16); }

// ---------------------------------------------------------------------------
__global__ void copy_f4_kernel(const float4* __restrict__ src, float4* __restrict__ dst, int n4) {
  int i = blockIdx.x * blockDim.x + threadIdx.x;
  if (i < n4) dst[i] = src[i];
}

__global__ void rel_proj_kernel(const float* __restrict__ r_x, const float* __restrict__ Wrel,
                                const float* __restrict__ brel, float* __restrict__ out) {
  int row = blockIdx.x;
  int c = threadIdx.x;
  if (c >= DD) return;
  float acc = brel[c];
  const float* rr = r_x + (size_t)row * (2 * DD);
  for (int k = 0; k < 2 * DD; ++k) acc += rr[k] * Wrel[(size_t)k * DD + c];
  out[(size_t)row * DD + c] = acc;
}

__global__ void hist_kernel(const int* __restrict__ dst, int* __restrict__ counts) {
  int e = blockIdx.x * blockDim.x + threadIdx.x;
  if (e < EE) atomicAdd(&counts[dst[e]], 1);
}

__global__ __launch_bounds__(1024) void scan_kernel(const int* __restrict__ counts,
                                                    int* __restrict__ row_ptr,
                                                    int* __restrict__ cursor) {
  __shared__ int sums[1024];
  const int n = NTOT;
  int t = threadIdx.x;
  const int chunk = (n + 1023) / 1024;
  int begin = t * chunk;
  int end = begin + chunk; if (end > n) end = n;
  int s = 0;
  for (int i = begin; i < end; ++i) s += counts[i];
  sums[t] = s;
  __syncthreads();
  for (int off = 1; off < 1024; off <<= 1) {
    int v = (t >= off) ? sums[t - off] : 0;
    __syncthreads();
    sums[t] += v;
    __syncthreads();
  }
  int run = sums[t] - s;
  for (int i = begin; i < end; ++i) {
    row_ptr[i] = run; cursor[i] = run;
    run += counts[i];
  }
  if (t == 1023) row_ptr[n] = sums[1023];
}

__global__ void scatter_kernel(const int* __restrict__ dst, const int* __restrict__ src,
                               const float* __restrict__ w, int* __restrict__ cursor,
                               int* __restrict__ src_s, float* __restrict__ w_s) {
  int e = blockIdx.x * blockDim.x + threadIdx.x;
  if (e < EE) {
    int pos = atomicAdd(&cursor[dst[e]], 1);
    src_s[pos] = src[e];
    w_s[pos] = w[e];
  }
}

__global__ void detect_mask_kernel(const unsigned* __restrict__ m0, const unsigned* __restrict__ m1,
                                   const unsigned* __restrict__ m2, const unsigned* __restrict__ m3,
                                   int* __restrict__ flag) {
  int idx = blockIdx.x * blockDim.x + threadIdx.x;
  const int wp = BB * LL / 4;
  if (idx >= 4 * wp) return;
  const unsigned* p = idx < wp ? m0 : idx < 2 * wp ? m1 : idx < 3 * wp ? m2 : m3;
  if (p[idx % wp] > 1u) atomicOr(flag, 1);
}

__global__ void norm_mask_kernel(const void* __restrict__ raw, int* __restrict__ outm,
                                 int* __restrict__ many, const int* __restrict__ flag) {
  int idx = blockIdx.x * blockDim.x + threadIdx.x;
  if (idx >= BB * LL) return;
  int v = (*flag) ? (int)((const unsigned char*)raw)[idx] : ((const int*)raw)[idx];
  v = v ? 1 : 0;
  outm[idx] = v;
  if (v) atomicOr(&many[idx >> 5], 1);
}

// aggregate with 8-edge unroll (8x MLP); writes split bf16 hi/lo at ld=KP1
__global__ __launch_bounds__(320) void aggregate_kernel(
    const float* __restrict__ feat, u16* __restrict__ outhi, u16* __restrict__ outlo,
    const int* __restrict__ row_ptr, const int* __restrict__ srcs, const float* __restrict__ ws) {
  int d = blockIdx.x;
  int f = threadIdx.x;
  if (f >= DD) return;
  int beg = row_ptr[d], end = row_ptr[d + 1];
  float acc = 0.f;
  int e = beg;
  for (; e + 8 <= end; e += 8) {
    int s[8]; float wv[8]; float v[8];
#pragma unroll
    for (int u = 0; u < 8; ++u) { s[u] = srcs[e + u]; wv[u] = ws[e + u]; }
#pragma unroll
    for (int u = 0; u < 8; ++u) v[u] = feat[(size_t)s[u] * DD + f];
#pragma unroll
    for (int u = 0; u < 8; ++u) acc += wv[u] * v[u];
  }
  for (; e + 2 <= end; e += 2) {
    int s0 = srcs[e], s1 = srcs[e + 1];
    float w0 = ws[e], w1 = ws[e + 1];
    acc += w0 * feat[(size_t)s0 * DD + f] + w1 * feat[(size_t)s1 * DD + f];
  }
  if (e < end) acc += ws[e] * feat[(size_t)srcs[e] * DD + f];
  u16 hi, lo; split2(acc, hi, lo);
  outhi[(size_t)d * KP1 + f] = hi;
  outlo[(size_t)d * KP1 + f] = lo;
}

__global__ void pad_zero_kernel(u16* __restrict__ hi, u16* __restrict__ lo, int rows, int ld, int c0) {
  int pw = ld - c0;
  int idx = blockIdx.x * blockDim.x + threadIdx.x;
  if (idx >= rows * pw) return;
  int r = idx / pw, c = c0 + idx % pw;
  hi[(size_t)r * ld + c] = 0;
  lo[(size_t)r * ld + c] = 0;
}

__global__ void transpose_split_kernel(const float* __restrict__ in, int insz,
                                       u16* __restrict__ outhi, u16* __restrict__ outlo, int outsz,
                                       int Kreal, int Nn, int Kpad) {
  int z = blockIdx.y;
  int idx = blockIdx.x * blockDim.x + threadIdx.x;
  if (idx >= Nn * Kpad) return;
  int n = idx / Kpad, k = idx % Kpad;
  float v = (k < Kreal) ? in[(size_t)z * insz + (size_t)k * Nn + n] : 0.f;
  u16 hi, lo; split2(v, hi, lo);
  outhi[(size_t)z * outsz + idx] = hi;
  outlo[(size_t)z * outsz + idx] = lo;
}

// ---------------------------------------------------------------------------
// split-bf16 MFMA GEMM (npass=3: ah*bh + ah*bl + al*bh; npass=1: ah*bh only).
// wofuse=1: M-chunks of 2048 map to (dir,side); epilogue routes into emAll
//           [4096 x KP2] at col range [dir*300, dir*300+300) with maskany zeroing.
// ---------------------------------------------------------------------------
__global__ __launch_bounds__(256, 2) void mfma_gemm_kernel(
    const u16* __restrict__ Ahi, const u16* __restrict__ Alo, int lda,
    const u16* __restrict__ Bhi, const u16* __restrict__ Blo, int ldb,
    int M, int Nn, int K, const int* __restrict__ g1,
    float* __restrict__ C, int ldc, int coloff,
    const float* __restrict__ bias, int dorelu, const int* __restrict__ rowmask,
    u16* __restrict__ Chi, u16* __restrict__ Clo, int ldc16,
    int npass, int wofuse) {
  __shared__ int4 sAh[512], sAl[512], sBh[512], sBl[512];
  const int tid = threadIdx.x;
  const int row0 = blockIdx.y * 128, col0 = blockIdx.x * 128;
  const int wave = tid >> 6, lane = tid & 63;
  const int wrow = (wave >> 1) * 64, wcol = (wave & 1) * 64;
  const int m16 = lane & 15, quad = lane >> 4;

  const int sr = tid >> 2, sc = tid & 3;
  const u16* pah[2]; const u16* pal[2]; bool va[2];
  const u16* pbh[2]; const u16* pbl[2]; bool vb[2];
  int sidx[2];
#pragma unroll
  for (int i = 0; i < 2; ++i) {
    int r = sr + i * 64;
    sidx[i] = r * 4 + (sc ^ ((r >> 1) & 3));
    int grow = row0 + r;
    va[i] = grow < M;
    int ar = va[i] ? (g1 ? g1[grow] : grow) : 0;
    pah[i] = Ahi + (size_t)ar * lda + sc * 8;
    pal[i] = Alo + (size_t)ar * lda + sc * 8;
    int gn = col0 + r;
    vb[i] = gn < Nn;
    int br = vb[i] ? gn : 0;
    pbh[i] = Bhi + (size_t)br * ldb + sc * 8;
    pbl[i] = Blo + (size_t)br * ldb + sc * 8;
  }
  int idxA[4], idxB[4];
#pragma unroll
  for (int f = 0; f < 4; ++f) {
    int r = wrow + f * 16 + m16;
    idxA[f] = r * 4 + (quad ^ ((r >> 1) & 3));
    int n = wcol + f * 16 + m16;
    idxB[f] = n * 4 + (quad ^ ((n >> 1) & 3));
  }
  f32x4 acc[4][4];
#pragma unroll
  for (int i = 0; i < 4; ++i)
#pragma unroll
    for (int j = 0; j < 4; ++j) acc[i][j] = (f32x4){0.f, 0.f, 0.f, 0.f};

  const int4 z4 = {0, 0, 0, 0};
  for (int k0 = 0; k0 < K; k0 += 32) {
#pragma unroll
    for (int i = 0; i < 2; ++i) {
      int4 vh = z4, vl = z4, wh = z4, wl = z4;
      if (va[i]) { vh = *(const int4*)(pah[i] + k0); vl = *(const int4*)(pal[i] + k0); }
      if (vb[i]) { wh = *(const int4*)(pbh[i] + k0); wl = *(const int4*)(pbl[i] + k0); }
      sAh[sidx[i]] = vh; sAl[sidx[i]] = vl;
      sBh[sidx[i]] = wh; sBl[sidx[i]] = wl;
    }
    __syncthreads();
    short8 ah[4], al[4], bh[4], bl[4];
#pragma unroll
    for (int f = 0; f < 4; ++f) {
      ah[f] = *(const short8*)&sAh[idxA[f]];
      al[f] = *(const short8*)&sAl[idxA[f]];
      bh[f] = *(const short8*)&sBh[idxB[f]];
      bl[f] = *(const short8*)&sBl[idxB[f]];
    }
#pragma unroll
    for (int i = 0; i < 4; ++i)
#pragma unroll
      for (int j = 0; j < 4; ++j)
        acc[i][j] = __builtin_amdgcn_mfma_f32_16x16x32_bf16(ah[i], bh[j], acc[i][j], 0, 0, 0);
    if (npass > 1) {
#pragma unroll
      for (int i = 0; i < 4; ++i)
#pragma unroll
        for (int j = 0; j < 4; ++j)
          acc[i][j] = __builtin_amdgcn_mfma_f32_16x16x32_bf16(ah[i], bl[j], acc[i][j], 0, 0, 0);
#pragma unroll
      for (int i = 0; i < 4; ++i)
#pragma unroll
        for (int j = 0; j < 4; ++j)
          acc[i][j] = __builtin_amdgcn_mfma_f32_16x16x32_bf16(al[i], bh[j], acc[i][j], 0, 0, 0);
    }
    __syncthreads();
  }
  // epilogue: C/D map col=lane&15, row=quad*4+reg
#pragma unroll
  for (int i = 0; i < 4; ++i) {
#pragma unroll
    for (int reg = 0; reg < 4; ++reg) {
      int row = row0 + wrow + i * 16 + quad * 4 + reg;
      if (row >= M) continue;
      if (wofuse) {
        int b = row & 2047, side = (row >> 11) & 1, dir = (row >> 12) & 1;
        bool zero = rowmask[(side * 2 + dir) * BB + b] == 0;
        int orow = side * 2048 + b;
#pragma unroll
        for (int j = 0; j < 4; ++j) {
          int col = col0 + wcol + j * 16 + m16;
          if (col >= Nn) continue;
          if ((col >= 300) != (dir != 0)) continue;  // col range [dir*300, dir*300+300)
          float v = acc[i][j][reg];
          if (zero) v = 0.f;
          u16 hb, lb; split2(v, hb, lb);
          Chi[(size_t)orow * ldc16 + col] = hb;
          Clo[(size_t)orow * ldc16 + col] = lb;
        }
        continue;
      }
      bool zero = (rowmask != nullptr) && (rowmask[row] == 0);
#pragma unroll
      for (int j = 0; j < 4; ++j) {
        int col = col0 + wcol + j * 16 + m16;
        if (col >= Nn) continue;
        float v = acc[i][j][reg];
        if (bias) v += bias[col];
        if (dorelu) v = fmaxf(v, 0.f);
        if (zero) v = 0.f;
        if (C) C[(size_t)row * ldc + coloff + col] = v;
        if (Chi) {
          u16 hb, lb; split2(v, hb, lb);
          Chi[(size_t)row * ldc16 + coloff + col] = hb;
          Clo[(size_t)row * ldc16 + coloff + col] = lb;
        }
      }
    }
  }
}

// ---------------------------------------------------------------------------
// attention over fused kv[row][512] (k: 0..255, v: 256..511). qb has stride 512.
__global__ __launch_bounds__(256) void attention_kernel(
    const float* __restrict__ qb, const float* __restrict__ kv,
    const int* __restrict__ head_seq, const int* __restrict__ rel_seq,
    const int* __restrict__ masks, u16* __restrict__ ctxhi, u16* __restrict__ ctxlo) {
  int b = blockIdx.x;
  int tid = threadIdx.x;
  __shared__ float qs[256];
  __shared__ float attns[8][33];
  __shared__ int hid[32], rid[32], ms[32];
  qs[tid] = qb[(size_t)b * 512 + tid];
  if (tid < 32) {
    hid[tid] = head_seq[b * LL + tid];
    rid[tid] = NE + rel_seq[b * LL + tid];
    ms[tid] = masks[b * LL + tid];
  }
  __syncthreads();
  int h = tid >> 5, l = tid & 31;
  const float4* k1 = (const float4*)(kv + (size_t)hid[l] * 512 + h * 32);
  const float4* k2 = (const float4*)(kv + (size_t)rid[l] * 512 + h * 32);
  float s = 0.f;
#pragma unroll
  for (int i = 0; i < 8; ++i) {
    float4 a = k1[i], c4 = k2[i];
    const float* qp = &qs[h * 32 + i * 4];
    s += qp[0] * (a.x + c4.x) + qp[1] * (a.y + c4.y) + qp[2] * (a.z + c4.z) + qp[3] * (a.w + c4.w);
  }
  s *= 0.17677669529663687f;
  s = ms[l] ? s : -1e9f;
  float m = s;
  for (int off = 16; off; off >>= 1) m = fmaxf(m, __shfl_xor(m, off, 32));
  float e = expf(s - m);
  float sum = e;
  for (int off = 16; off; off >>= 1) sum += __shfl_xor(sum, off, 32);
  attns[h][l] = e / sum;
  __syncthreads();
  int d = tid & 31;
  float c = 0.f;
#pragma unroll 4
  for (int l2 = 0; l2 < 32; ++l2) {
    float a = attns[h][l2];
    float v = kv[(size_t)hid[l2] * 512 + 256 + h * 32 + d] +
              kv[(size_t)rid[l2] * 512 + 256 + h * 32 + d];
    c += a * v;
  }
  u16 hb, lb; split2(c, hb, lb);
  ctxhi[(size_t)b * 256 + tid] = hb;
  ctxlo[(size_t)b * 256 + tid] = lb;
}

__global__ void gather_part_kernel(const u16* __restrict__ enthi, const u16* __restrict__ entlo,
                                   const int* __restrict__ ids, float* __restrict__ out) {
  int b = blockIdx.x;
  int t = threadIdx.x;
  if (t < DD) {
    size_t o = (size_t)ids[b] * KP1 + t;
    out[(size_t)b * 600 + t] = bf2f(enthi[o]) + bf2f(entlo[o]);
  }
}

__global__ __launch_bounds__(256) void rownorm_kernel(const float* __restrict__ rows,
                                                      u16* __restrict__ outhi,
                                                      u16* __restrict__ outlo) {
  int b = blockIdx.x;
  int t = threadIdx.x;
  const float* rp = rows + (size_t)b * 600;
  float s = 0.f;
  for (int c = t; c < 600; c += 256) { float v = rp[c]; s += v * v; }
  __shared__ float red[256];
  red[t] = s;
  __syncthreads();
  for (int off = 128; off; off >>= 1) {
    if (t < off) red[t] += red[t + off];
    __syncthreads();
  }
  __shared__ float inv;
  if (t == 0) inv = 1.f / fmaxf(sqrtf(red[0]), 1e-8f);
  __syncthreads();
  for (int c = t; c < KP2; c += 256) {
    float v = (c < 600) ? rp[c] * inv : 0.f;
    u16 hb, lb; split2(v, hb, lb);
    outhi[(size_t)b * KP2 + c] = hb;
    outlo[(size_t)b * KP2 + c] = lb;
  }
}

__global__ __launch_bounds__(256) void loss_reduce_kernel(const float* __restrict__ sim,
                                                          double* __restrict__ accum) {
  __shared__ float rn_[256], rp_[256];
  float negs = 0.f, poss = 0.f;
  for (int idx = blockIdx.x * blockDim.x + threadIdx.x; idx < BB * BB;
       idx += gridDim.x * blockDim.x) {
    int i = idx >> 11, j = idx & (BB - 1);
    float s = sim[idx];
    if (i == j) {
      negs += 0.2f;
      poss += fminf(s, 0.9f);
    } else {
      negs += fmaxf(s, 0.2f);
    }
  }
  rn_[threadIdx.x] = negs; rp_[threadIdx.x] = poss;
  __syncthreads();
  for (int off = 128; off; off >>= 1) {
    if (threadIdx.x < off) {
      rn_[threadIdx.x] += rn_[threadIdx.x + off];
      rp_[threadIdx.x] += rp_[threadIdx.x + off];
    }
    __syncthreads();
  }
  if (threadIdx.x == 0) {
    atomicAdd(&accum[0], (double)rn_[0]);
    atomicAdd(&accum[1], (double)rp_[0]);
  }
}

__global__ void finalize_kernel(const double* __restrict__ accum, float* __restrict__ out) {
  double neg = accum[0] / ((double)BB * (double)BB);
  double pos = accum[1] / (double)BB;
  out[0] = (float)(neg - 0.2 - pos + 0.9);
}

// ---------------------------------------------------------------------------
static inline void launch_mfma(hipStream_t st, const u16* Ahi, const u16* Alo, int lda,
                               const u16* Bhi, const u16* Blo, int ldb, int M, int Nn, int K,
                               const int* g1, float* C, int ldc, int coloff, const float* bias,
                               int dorelu, const int* rowmask, u16* Chi, u16* Clo, int ldc16,
                               int npass = 3, int wofuse = 0) {
  dim3 grid((Nn + 127) / 128, (M + 127) / 128);
  mfma_gemm_kernel<<<grid, 256, 0, st>>>(Ahi, Alo, lda, Bhi, Blo, ldb, M, Nn, K, g1, C, ldc,
                                         coloff, bias, dorelu, rowmask, Chi, Clo, ldc16, npass,
                                         wofuse);
}

extern "C" void kernel_launch(void* const* d_in, const int* in_sizes, int n_in,
                              void* d_out, int out_size, void* d_ws, size_t ws_size,
                              hipStream_t stream) {
  const float* e_x    = (const float*)d_in[0];
  const float* r_x    = (const float*)d_in[1];
  const float* edge_w = (const float*)d_in[2];
  const float* Wrel   = (const float*)d_in[3];
  const float* brel   = (const float*)d_in[4];
  const float* W1     = (const float*)d_in[5];
  const float* b1     = (const float*)d_in[6];
  const float* W2     = (const float*)d_in[7];
  const float* b2     = (const float*)d_in[8];
  const float* Wprox  = (const float*)d_in[9];
  const float* bprox  = (const float*)d_in[10];
  const float* Wq     = (const float*)d_in[11];
  const float* Wk     = (const float*)d_in[12];
  const float* Wv     = (const float*)d_in[13];
  const float* Wo     = (const float*)d_in[14];
  const int* edge_src = (const int*)d_in[15];
  const int* edge_dst = (const int*)d_in[16];
  const int* l_ids    = (const int*)d_in[17];
  const int* r_ids    = (const int*)d_in[18];
  float* out = (float*)d_out;

  // ---- workspace ----
  char* base = (char*)d_ws;
  size_t off = 0;
  auto nxt = [&](size_t bytes) -> char* {
    char* p = base + off;
    off += (bytes + 63) & ~(size_t)63;
    return p;
  };
  char* R0 = nxt(64512000);   // x fp32 / h2 hi+lo (NTOT*KP1 each)
  char* R1 = nxt(64512000);   // agg hi+lo -> kv fp32 (spans into R2) -> simbuf
  char* R2 = nxt(60480000);   // h1 fp32 -> kv spill
  float* qbufL = (float*)nxt(4194304);   // BB x 512
  float* qbufR = (float*)nxt(4194304);
  u16* ctxAhi = (u16*)nxt(4194304);      // 4 x BB x 256
  u16* ctxAlo = (u16*)nxt(4194304);
  u16* emAhi  = (u16*)nxt(4980736);      // 4096 x KP2
  u16* emAlo  = (u16*)nxt(4980736);
  u16* lnhi   = (u16*)nxt(2490368);      // BB x KP2
  u16* lnlo   = (u16*)nxt(2490368);
  u16* rnhi   = (u16*)nxt(2490368);
  u16* rnlo   = (u16*)nxt(2490368);
  u16* qkvhi  = (u16*)nxt(983040);       // 6 x [256 x KP1]: q0,q1,k0,v0,k1,v1
  u16* qkvlo  = (u16*)nxt(983040);
  u16* w12hi  = (u16*)nxt(384000);       // 2 x [300 x KP1]
  u16* w12lo  = (u16*)nxt(384000);
  u16* wohi   = (u16*)nxt(307200);       // [600 x 256] (dir0 rows 0-299, dir1 rows 300-599)
  u16* wolo   = (u16*)nxt(307200);
  u16* wpxhi  = (u16*)nxt(364800);       // [300 x KP2]
  u16* wpxlo  = (u16*)nxt(364800);
  double* accum = (double*)nxt(16);
  int* row_ptr  = (int*)nxt(4 * (NTOT + 1));
  int* cursor   = (int*)nxt(4 * NTOT);
  int* counts   = (int*)nxt(4 * NTOT);
  int* src_s    = (int*)nxt(4 * EE);
  float* w_s    = (float*)nxt(4 * EE);
  int* mask_norm = (int*)nxt(4 * 4 * BB * LL);
  int* maskany   = (int*)nxt(4 * 4 * BB);
  int* flag      = (int*)nxt(64);

  float* xbuf = (float*)R0;
  u16* h2hi = (u16*)R0;  u16* h2lo = h2hi + (size_t)NTOT * KP1;
  u16* agghi = (u16*)R1; u16* agglo = agghi + (size_t)NTOT * KP1;
  float* kvbuf = (float*)R1;   // NTOT x 512 fp32 = 103 MB, spans R1+R2
  float* h1 = (float*)R2;
  float* simbuf = (float*)R1;  // after kv is dead

  hipMemsetAsync(counts, 0, NTOT * sizeof(int), stream);
  hipMemsetAsync(maskany, 0, 4 * BB * sizeof(int), stream);
  hipMemsetAsync(flag, 0, sizeof(int), stream);
  hipMemsetAsync(accum, 0, 2 * sizeof(double), stream);

  // x = [e_x ; r_x @ Wrel + brel]
  copy_f4_kernel<<<(3750000 + 255) / 256, 256, 0, stream>>>((const float4*)e_x, (float4*)xbuf,
                                                            3750000);
  rel_proj_kernel<<<NR, 320, 0, stream>>>(r_x, Wrel, brel, xbuf + (size_t)NE * DD);

  // CSR
  hist_kernel<<<(EE + 255) / 256, 256, 0, stream>>>(edge_dst, counts);
  scan_kernel<<<1, 1024, 0, stream>>>(counts, row_ptr, cursor);
  scatter_kernel<<<(EE + 255) / 256, 256, 0, stream>>>(edge_dst, edge_src, edge_w, cursor, src_s,
                                                       w_s);

  // masks
  detect_mask_kernel<<<256, 256, 0, stream>>>((const unsigned*)d_in[21], (const unsigned*)d_in[24],
                                              (const unsigned*)d_in[27], (const unsigned*)d_in[30],
                                              flag);
  for (int mi = 0; mi < 4; ++mi)
    norm_mask_kernel<<<(BB * LL + 255) / 256, 256, 0, stream>>>(
        d_in[21 + mi * 3], mask_norm + (size_t)mi * BB * LL, maskany + mi * BB, flag);

  // weight transposes: qkv layout q0,q1,k0,v0,k1,v1 (each [256 x KP1])
  transpose_split_kernel<<<dim3((256 * KP1 + 255) / 256, 2), 256, 0, stream>>>(
      Wq, 300 * 256, qkvhi + 0 * 81920, qkvlo + 0 * 81920, 81920, 300, 256, KP1);
  transpose_split_kernel<<<dim3((256 * KP1 + 255) / 256, 1), 256, 0, stream>>>(
      Wk, 0, qkvhi + 2 * 81920, qkvlo + 2 * 81920, 81920, 300, 256, KP1);
  transpose_split_kernel<<<dim3((256 * KP1 + 255) / 256, 1), 256, 0, stream>>>(
      Wv, 0, qkvhi + 3 * 81920, qkvlo + 3 * 81920, 81920, 300, 256, KP1);
  transpose_split_kernel<<<dim3((256 * KP1 + 255) / 256, 1), 256, 0, stream>>>(
      Wk + 300 * 256, 0, qkvhi + 4 * 81920, qkvlo + 4 * 81920, 81920, 300, 256, KP1);
  transpose_split_kernel<<<dim3((256 * KP1 + 255) / 256, 1), 256, 0, stream>>>(
      Wv + 300 * 256, 0, qkvhi + 5 * 81920, qkvlo + 5 * 81920, 81920, 300, 256, KP1);
  transpose_split_kernel<<<dim3((300 * KP1 + 255) / 256, 1), 256, 0, stream>>>(
      W1, 0, w12hi, w12lo, 96000, 300, 300, KP1);
  transpose_split_kernel<<<dim3((300 * KP1 + 255) / 256, 1), 256, 0, stream>>>(
      W2, 0, w12hi + 96000, w12lo + 96000, 96000, 300, 300, KP1);
  transpose_split_kernel<<<dim3((300 * 256 + 255) / 256, 2), 256, 0, stream>>>(
      Wo, 256 * 300, wohi, wolo, 76800, 256, 300, 256);
  transpose_split_kernel<<<dim3((300 * KP2 + 255) / 256, 1), 256, 0, stream>>>(
      Wprox, 0, wpxhi, wpxlo, 182400, 600, 300, KP2);

  // K-pad zeroing
  pad_zero_kernel<<<(NTOT * 20 + 255) / 256, 256, 0, stream>>>(agghi, agglo, NTOT, KP1, 300);
  pad_zero_kernel<<<(4096 * 8 + 255) / 256, 256, 0, stream>>>(emAhi, emAlo, 4096, KP2, 600);

  // GCN
  aggregate_kernel<<<NTOT, 320, 0, stream>>>(xbuf, agghi, agglo, row_ptr, src_s, w_s);
  launch_mfma(stream, agghi, agglo, KP1, w12hi, w12lo, KP1, NTOT, 300, KP1, nullptr, h1, 300, 0,
              b1, 1, nullptr, nullptr, nullptr, 0);
  aggregate_kernel<<<NTOT, 320, 0, stream>>>(h1, agghi, agglo, row_ptr, src_s, w_s);
  pad_zero_kernel<<<(NTOT * 20 + 255) / 256, 256, 0, stream>>>(h2hi, h2lo, NTOT, KP1, 300);
  launch_mfma(stream, agghi, agglo, KP1, w12hi + 96000, w12lo + 96000, KP1, NTOT, 300, KP1,
              nullptr, nullptr, 0, 0, b2, 0, nullptr, h2hi, h2lo, KP1);

  // q (batched per side, N=512: dirs 0|1)
  launch_mfma(stream, h2hi, h2lo, KP1, qkvhi, qkvlo, KP1, BB, 512, KP1, l_ids, qbufL, 512, 0,
              nullptr, 0, nullptr, nullptr, nullptr, 0);
  launch_mfma(stream, h2hi, h2lo, KP1, qkvhi, qkvlo, KP1, BB, 512, KP1, r_ids, qbufR, 512, 0,
              nullptr, 0, nullptr, nullptr, nullptr, 0);

  // encoders: fused kv per dir, then attention into ctxAll chunk (dir*2+side)
  for (int dir = 0; dir < 2; ++dir) {
    launch_mfma(stream, h2hi, h2lo, KP1, qkvhi + (2 + 2 * dir) * 81920,
                qkvlo + (2 + 2 * dir) * 81920, KP1, NTOT, 512, KP1, nullptr, kvbuf, 512, 0,
                nullptr, 0, nullptr, nullptr, nullptr, 0);
    for (int side = 0; side < 2; ++side) {
      int mi = side * 2 + dir;
      const int* rel_seq  = (const int*)d_in[19 + side * 6 + dir * 3];
      const int* head_seq = (const int*)d_in[20 + side * 6 + dir * 3];
      const float* qb = (side ? qbufR : qbufL) + dir * 256;
      size_t cidx = (size_t)(dir * 2 + side) * BB * 256;
      attention_kernel<<<BB, 256, 0, stream>>>(qb, kvbuf, head_seq, rel_seq,
                                               mask_norm + (size_t)mi * BB * LL,
                                               ctxAhi + cidx, ctxAlo + cidx);
    }
  }

  // Wo (batched): M=8192 over ctxAll, N=600 block-diag, epilogue routes into emAll
  launch_mfma(stream, ctxAhi, ctxAlo, 256, wohi, wolo, 256, 4 * BB, 600, 256, nullptr, nullptr,
              0, 0, nullptr, 0, maskany, emAhi, emAlo, KP2, 3, 1);

  // proximity (batched, M=4096 writes lem rows then rem rows — contiguous in d_out)
  float* lem = out + 1;
  float* rem = out + 1 + (size_t)BB * 600;
  launch_mfma(stream, emAhi, emAlo, KP2, wpxhi, wpxlo, KP2, 4096, 300, KP2, nullptr, lem, 600,
              300, bprox, 0, nullptr, nullptr, nullptr, 0);
  gather_part_kernel<<<BB, 320, 0, stream>>>(h2hi, h2lo, l_ids, lem);
  gather_part_kernel<<<BB, 320, 0, stream>>>(h2hi, h2lo, r_ids, rem);

  // cosine similarity + loss (sim: 1-pass bf16 — feeds only the clamped mean)
  rownorm_kernel<<<BB, 256, 0, stream>>>(lem, lnhi, lnlo);
  rownorm_kernel<<<BB, 256, 0, stream>>>(rem, rnhi, rnlo);
  launch_mfma(stream, lnhi, lnlo, KP2, rnhi, rnlo, KP2, BB, BB, KP2, nullptr, simbuf, BB, 0,
              nullptr, 0, nullptr, nullptr, nullptr, 0, 1, 0);
  loss_reduce_kernel<<<2048, 256, 0, stream>>>(simbuf, accum);
  finalize_kernel<<<1, 1, 0, stream>>>(accum, out);
}

// Round 5
// 1408.553 us; speedup vs baseline: 2.6060x; 1.0314x over previous
//
#include <hip/hip_runtime.h>
#include <cstdint>
#include <cstddef>

typedef _Float16 f16;
typedef __attribute__((ext_vector_type(8))) _Float16 half8;
typedef __attribute__((ext_vector_type(4))) float f32x4;

#define NE 50000
#define NR 400
#define DD 300
#define NTOT 50400
#define EE 800000
#define BB 2048
#define LL 32
#define HD 256
#define KP1 320
#define KP2 608

// split fp32 into fp16 hi + fp16 lo (22-bit combined mantissa)
__device__ inline void split2h(float x, f16& hi, f16& lo) {
  f16 h = (f16)x;
  hi = h;
  lo = (f16)(x - (float)h);
}

// ---------------------------------------------------------------------------
__global__ void copy_f4_kernel(const float4* __restrict__ src, float4* __restrict__ dst, int n4) {
  int i = blockIdx.x * blockDim.x + threadIdx.x;
  if (i < n4) dst[i] = src[i];
}

__global__ void rel_proj_kernel(const float* __restrict__ r_x, const float* __restrict__ Wrel,
                                const float* __restrict__ brel, float* __restrict__ out) {
  int row = blockIdx.x;
  int c = threadIdx.x;
  if (c >= DD) return;
  float acc = brel[c];
  const float* rr = r_x + (size_t)row * (2 * DD);
  for (int k = 0; k < 2 * DD; ++k) acc += rr[k] * Wrel[(size_t)k * DD + c];
  out[(size_t)row * DD + c] = acc;
}

__global__ void hist_kernel(const int* __restrict__ dst, int* __restrict__ counts) {
  int e = blockIdx.x * blockDim.x + threadIdx.x;
  if (e < EE) atomicAdd(&counts[dst[e]], 1);
}

__global__ __launch_bounds__(1024) void scan_kernel(const int* __restrict__ counts,
                                                    int* __restrict__ row_ptr,
                                                    int* __restrict__ cursor) {
  __shared__ int sums[1024];
  const int n = NTOT;
  int t = threadIdx.x;
  const int chunk = (n + 1023) / 1024;
  int begin = t * chunk;
  int end = begin + chunk; if (end > n) end = n;
  int s = 0;
  for (int i = begin; i < end; ++i) s += counts[i];
  sums[t] = s;
  __syncthreads();
  for (int off = 1; off < 1024; off <<= 1) {
    int v = (t >= off) ? sums[t - off] : 0;
    __syncthreads();
    sums[t] += v;
    __syncthreads();
  }
  int run = sums[t] - s;
  for (int i = begin; i < end; ++i) {
    row_ptr[i] = run; cursor[i] = run;
    run += counts[i];
  }
  if (t == 1023) row_ptr[n] = sums[1023];
}

__global__ void scatter_kernel(const int* __restrict__ dst, const int* __restrict__ src,
                               const float* __restrict__ w, int* __restrict__ cursor,
                               int* __restrict__ src_s, float* __restrict__ w_s) {
  int e = blockIdx.x * blockDim.x + threadIdx.x;
  if (e < EE) {
    int pos = atomicAdd(&cursor[dst[e]], 1);
    src_s[pos] = src[e];
    w_s[pos] = w[e];
  }
}

__global__ void detect_mask_kernel(const unsigned* __restrict__ m0, const unsigned* __restrict__ m1,
                                   const unsigned* __restrict__ m2, const unsigned* __restrict__ m3,
                                   int* __restrict__ flag) {
  int idx = blockIdx.x * blockDim.x + threadIdx.x;
  const int wp = BB * LL / 4;
  if (idx >= 4 * wp) return;
  const unsigned* p = idx < wp ? m0 : idx < 2 * wp ? m1 : idx < 3 * wp ? m2 : m3;
  if (p[idx % wp] > 1u) atomicOr(flag, 1);
}

__global__ void norm_mask_kernel(const void* __restrict__ raw, int* __restrict__ outm,
                                 int* __restrict__ many, const int* __restrict__ flag) {
  int idx = blockIdx.x * blockDim.x + threadIdx.x;
  if (idx >= BB * LL) return;
  int v = (*flag) ? (int)((const unsigned char*)raw)[idx] : ((const int*)raw)[idx];
  v = v ? 1 : 0;
  outm[idx] = v;
  if (v) atomicOr(&many[idx >> 5], 1);
}

__global__ void concat_ids_kernel(const int* __restrict__ a, const int* __restrict__ b,
                                  int* __restrict__ o) {
  int i = blockIdx.x * blockDim.x + threadIdx.x;
  if (i < BB) o[i] = a[i];
  else if (i < 2 * BB) o[i] = b[i - BB];
}

// aggregate with 8-edge unroll; writes split fp16 hi/lo at ld=KP1
__global__ __launch_bounds__(320) void aggregate_kernel(
    const float* __restrict__ feat, f16* __restrict__ outhi, f16* __restrict__ outlo,
    const int* __restrict__ row_ptr, const int* __restrict__ srcs, const float* __restrict__ ws) {
  int d = blockIdx.x;
  int f = threadIdx.x;
  if (f >= DD) return;
  int beg = row_ptr[d], end = row_ptr[d + 1];
  float acc = 0.f;
  int e = beg;
  for (; e + 8 <= end; e += 8) {
    int s[8]; float wv[8]; float v[8];
#pragma unroll
    for (int u = 0; u < 8; ++u) { s[u] = srcs[e + u]; wv[u] = ws[e + u]; }
#pragma unroll
    for (int u = 0; u < 8; ++u) v[u] = feat[(size_t)s[u] * DD + f];
#pragma unroll
    for (int u = 0; u < 8; ++u) acc += wv[u] * v[u];
  }
  for (; e + 2 <= end; e += 2) {
    int s0 = srcs[e], s1 = srcs[e + 1];
    float w0 = ws[e], w1 = ws[e + 1];
    acc += w0 * feat[(size_t)s0 * DD + f] + w1 * feat[(size_t)s1 * DD + f];
  }
  if (e < end) acc += ws[e] * feat[(size_t)srcs[e] * DD + f];
  f16 hi, lo; split2h(acc, hi, lo);
  outhi[(size_t)d * KP1 + f] = hi;
  outlo[(size_t)d * KP1 + f] = lo;
}

__global__ void pad_zero_kernel(f16* __restrict__ hi, f16* __restrict__ lo, int rows, int ld, int c0) {
  int pw = ld - c0;
  int idx = blockIdx.x * blockDim.x + threadIdx.x;
  if (idx >= rows * pw) return;
  int r = idx / pw, c = c0 + idx % pw;
  hi[(size_t)r * ld + c] = (f16)0.f;
  lo[(size_t)r * ld + c] = (f16)0.f;
}

// LDS-tiled coalesced transpose+split: in fp32 [Kreal x Nn] (z-batched) -> f16 hi/lo [Nn x Kpad]
__global__ __launch_bounds__(256) void transpose_split_kernel(
    const float* __restrict__ in, int insz, f16* __restrict__ outhi, f16* __restrict__ outlo,
    int outsz, int Kreal, int Nn, int Kpad) {
  __shared__ float tile[32][33];
  int z = blockIdx.z;
  int k0 = blockIdx.x * 32, n0 = blockIdx.y * 32;
  int tx = threadIdx.x & 31, ty = threadIdx.x >> 5;
#pragma unroll
  for (int r = 0; r < 4; ++r) {
    int k = k0 + ty + r * 8, n = n0 + tx;
    float v = (k < Kreal && n < Nn) ? in[(size_t)z * insz + (size_t)k * Nn + n] : 0.f;
    tile[ty + r * 8][tx] = v;
  }
  __syncthreads();
#pragma unroll
  for (int r = 0; r < 4; ++r) {
    int n = n0 + ty + r * 8, k = k0 + tx;
    if (n < Nn && k < Kpad) {
      f16 h, l; split2h(tile[tx][ty + r * 8], h, l);
      outhi[(size_t)z * outsz + (size_t)n * Kpad + k] = h;
      outlo[(size_t)z * outsz + (size_t)n * Kpad + k] = l;
    }
  }
}

// ---------------------------------------------------------------------------
// split-fp16 MFMA GEMM: C = gather(A) @ B^T
//   npass=1: ah*bh            (~fp16 precision)
//   npass=2: + al*bh          (A exact to 2^-22, B rounded to fp16: rel ~2^-12)
//   npass=3: + ah*bl          (rel ~2^-22, fp32-grade)
// wofuse: M-chunks of 2048 = (dir,side); route into emAll[4096 x KP2] cols dir*300..+300
// losfuse: fused clamped-mean loss reduction (no C written)
// ---------------------------------------------------------------------------
__global__ __launch_bounds__(256, 2) void mfma_gemm_kernel(
    const f16* __restrict__ Ahi, const f16* __restrict__ Alo, int lda,
    const f16* __restrict__ Bhi, const f16* __restrict__ Blo, int ldb,
    int M, int Nn, int K, const int* __restrict__ g1,
    float* __restrict__ C, int ldc, int coloff,
    const float* __restrict__ bias, int dorelu, const int* __restrict__ rowmask,
    f16* __restrict__ Chi, f16* __restrict__ Clo, int ldc16,
    int npass, int wofuse, int losfuse, double* __restrict__ accum) {
  __shared__ int4 sAh[512], sAl[512], sBh[512], sBl[512];
  const int tid = threadIdx.x;
  const int row0 = blockIdx.y * 128, col0 = blockIdx.x * 128;
  const int wave = tid >> 6, lane = tid & 63;
  const int wrow = (wave >> 1) * 64, wcol = (wave & 1) * 64;
  const int m16 = lane & 15, quad = lane >> 4;

  const int sr = tid >> 2, sc = tid & 3;
  const f16* pah[2]; const f16* pal[2]; bool va[2];
  const f16* pbh[2]; const f16* pbl[2]; bool vb[2];
  int sidx[2];
#pragma unroll
  for (int i = 0; i < 2; ++i) {
    int r = sr + i * 64;
    sidx[i] = r * 4 + (sc ^ ((r >> 1) & 3));
    int grow = row0 + r;
    va[i] = grow < M;
    int ar = va[i] ? (g1 ? g1[grow] : grow) : 0;
    pah[i] = Ahi + (size_t)ar * lda + sc * 8;
    pal[i] = Alo + (size_t)ar * lda + sc * 8;
    int gn = col0 + r;
    vb[i] = gn < Nn;
    int br = vb[i] ? gn : 0;
    pbh[i] = Bhi + (size_t)br * ldb + sc * 8;
    pbl[i] = Blo + (size_t)br * ldb + sc * 8;
  }
  int idxA[4], idxB[4];
#pragma unroll
  for (int f = 0; f < 4; ++f) {
    int r = wrow + f * 16 + m16;
    idxA[f] = r * 4 + (quad ^ ((r >> 1) & 3));
    int n = wcol + f * 16 + m16;
    idxB[f] = n * 4 + (quad ^ ((n >> 1) & 3));
  }
  f32x4 acc[4][4];
#pragma unroll
  for (int i = 0; i < 4; ++i)
#pragma unroll
    for (int j = 0; j < 4; ++j) acc[i][j] = (f32x4){0.f, 0.f, 0.f, 0.f};

  const int4 z4 = {0, 0, 0, 0};
  for (int k0 = 0; k0 < K; k0 += 32) {
#pragma unroll
    for (int i = 0; i < 2; ++i) {
      int4 vh = z4, wh = z4;
      if (va[i]) vh = *(const int4*)(pah[i] + k0);
      if (vb[i]) wh = *(const int4*)(pbh[i] + k0);
      sAh[sidx[i]] = vh; sBh[sidx[i]] = wh;
      if (npass >= 2) {
        int4 vl = z4;
        if (va[i]) vl = *(const int4*)(pal[i] + k0);
        sAl[sidx[i]] = vl;
      }
      if (npass >= 3) {
        int4 wl = z4;
        if (vb[i]) wl = *(const int4*)(pbl[i] + k0);
        sBl[sidx[i]] = wl;
      }
    }
    __syncthreads();
    half8 ah[4], bh[4];
#pragma unroll
    for (int f = 0; f < 4; ++f) {
      ah[f] = *(const half8*)&sAh[idxA[f]];
      bh[f] = *(const half8*)&sBh[idxB[f]];
    }
#pragma unroll
    for (int i = 0; i < 4; ++i)
#pragma unroll
      for (int j = 0; j < 4; ++j)
        acc[i][j] = __builtin_amdgcn_mfma_f32_16x16x32_f16(ah[i], bh[j], acc[i][j], 0, 0, 0);
    if (npass >= 2) {
      half8 al[4];
#pragma unroll
      for (int f = 0; f < 4; ++f) al[f] = *(const half8*)&sAl[idxA[f]];
#pragma unroll
      for (int i = 0; i < 4; ++i)
#pragma unroll
        for (int j = 0; j < 4; ++j)
          acc[i][j] = __builtin_amdgcn_mfma_f32_16x16x32_f16(al[i], bh[j], acc[i][j], 0, 0, 0);
    }
    if (npass >= 3) {
      half8 bl[4];
#pragma unroll
      for (int f = 0; f < 4; ++f) bl[f] = *(const half8*)&sBl[idxB[f]];
#pragma unroll
      for (int i = 0; i < 4; ++i)
#pragma unroll
        for (int j = 0; j < 4; ++j)
          acc[i][j] = __builtin_amdgcn_mfma_f32_16x16x32_f16(ah[i], bl[j], acc[i][j], 0, 0, 0);
    }
    __syncthreads();
  }

  if (losfuse) {
    // clamped-mean loss over sim tile; M=N=2048 exact
    float negs = 0.f, poss = 0.f;
#pragma unroll
    for (int i = 0; i < 4; ++i)
#pragma unroll
      for (int reg = 0; reg < 4; ++reg) {
        int row = row0 + wrow + i * 16 + quad * 4 + reg;
#pragma unroll
        for (int j = 0; j < 4; ++j) {
          int col = col0 + wcol + j * 16 + m16;
          float s = acc[i][j][reg];
          if (row == col) { negs += 0.2f; poss += fminf(s, 0.9f); }
          else negs += fmaxf(s, 0.2f);
        }
      }
    float* rn_ = (float*)sAh;
    float* rp_ = (float*)sAl;
    rn_[tid] = negs; rp_[tid] = poss;
    __syncthreads();
    for (int off2 = 128; off2; off2 >>= 1) {
      if (tid < off2) { rn_[tid] += rn_[tid + off2]; rp_[tid] += rp_[tid + off2]; }
      __syncthreads();
    }
    if (tid == 0) {
      atomicAdd(&accum[0], (double)rn_[0]);
      atomicAdd(&accum[1], (double)rp_[0]);
    }
    return;
  }

  // epilogue: C/D map col=lane&15, row=quad*4+reg
#pragma unroll
  for (int i = 0; i < 4; ++i) {
#pragma unroll
    for (int reg = 0; reg < 4; ++reg) {
      int row = row0 + wrow + i * 16 + quad * 4 + reg;
      if (row >= M) continue;
      if (wofuse) {
        int b = row & 2047, side = (row >> 11) & 1, dir = (row >> 12) & 1;
        bool zero = rowmask[(side * 2 + dir) * BB + b] == 0;
        int orow = side * 2048 + b;
#pragma unroll
        for (int j = 0; j < 4; ++j) {
          int col = col0 + wcol + j * 16 + m16;
          if (col >= Nn) continue;
          if ((col >= 300) != (dir != 0)) continue;
          float v = acc[i][j][reg];
          if (zero) v = 0.f;
          f16 hb, lb; split2h(v, hb, lb);
          Chi[(size_t)orow * ldc16 + col] = hb;
          Clo[(size_t)orow * ldc16 + col] = lb;
        }
        continue;
      }
      bool zero = (rowmask != nullptr) && (rowmask[row] == 0);
#pragma unroll
      for (int j = 0; j < 4; ++j) {
        int col = col0 + wcol + j * 16 + m16;
        if (col >= Nn) continue;
        float v = acc[i][j][reg];
        if (bias) v += bias[col];
        if (dorelu) v = fmaxf(v, 0.f);
        if (zero) v = 0.f;
        if (C) C[(size_t)row * ldc + coloff + col] = v;
        if (Chi) {
          f16 hb, lb; split2h(v, hb, lb);
          Chi[(size_t)row * ldc16 + coloff + col] = hb;
          Clo[(size_t)row * ldc16 + coloff + col] = lb;
        }
      }
    }
  }
}

// ---------------------------------------------------------------------------
// attention over fused kv[row][512] (k: 0..255, v: 256..511); grid.y = side
__global__ __launch_bounds__(256) void attention_kernel(
    const float* __restrict__ qAll, const float* __restrict__ kv,
    const int* __restrict__ h0, const int* __restrict__ r0, const int* __restrict__ m0,
    const int* __restrict__ h1, const int* __restrict__ r1, const int* __restrict__ m1,
    int dirOfs, f16* __restrict__ ctxhi, f16* __restrict__ ctxlo) {
  int b = blockIdx.x;
  int side = blockIdx.y;
  int tid = threadIdx.x;
  const int* hs = side ? h1 : h0;
  const int* rs = side ? r1 : r0;
  const int* msk = side ? m1 : m0;
  __shared__ float qs[256];
  __shared__ float attns[8][33];
  __shared__ int hid[32], rid[32], ms[32];
  qs[tid] = qAll[((size_t)(side * BB + b)) * 512 + dirOfs + tid];
  if (tid < 32) {
    hid[tid] = hs[b * LL + tid];
    rid[tid] = NE + rs[b * LL + tid];
    ms[tid] = msk[b * LL + tid];
  }
  __syncthreads();
  int h = tid >> 5, l = tid & 31;
  const float4* k1 = (const float4*)(kv + (size_t)hid[l] * 512 + h * 32);
  const float4* k2 = (const float4*)(kv + (size_t)rid[l] * 512 + h * 32);
  float s = 0.f;
#pragma unroll
  for (int i = 0; i < 8; ++i) {
    float4 a = k1[i], c4 = k2[i];
    const float* qp = &qs[h * 32 + i * 4];
    s += qp[0] * (a.x + c4.x) + qp[1] * (a.y + c4.y) + qp[2] * (a.z + c4.z) + qp[3] * (a.w + c4.w);
  }
  s *= 0.17677669529663687f;
  s = ms[l] ? s : -1e9f;
  float m = s;
  for (int off = 16; off; off >>= 1) m = fmaxf(m, __shfl_xor(m, off, 32));
  float e = expf(s - m);
  float sum = e;
  for (int off = 16; off; off >>= 1) sum += __shfl_xor(sum, off, 32);
  attns[h][l] = e / sum;
  __syncthreads();
  int d = tid & 31;
  float c = 0.f;
#pragma unroll 4
  for (int l2 = 0; l2 < 32; ++l2) {
    float a = attns[h][l2];
    float v = kv[(size_t)hid[l2] * 512 + 256 + h * 32 + d] +
              kv[(size_t)rid[l2] * 512 + 256 + h * 32 + d];
    c += a * v;
  }
  f16 hb, lb; split2h(c, hb, lb);
  size_t o = ((size_t)side * BB + b) * 256 + tid;
  ctxhi[o] = hb;
  ctxlo[o] = lb;
}

__global__ void gather_part_kernel(const f16* __restrict__ enthi, const f16* __restrict__ entlo,
                                   const int* __restrict__ ids, float* __restrict__ out) {
  int b = blockIdx.x;
  int t = threadIdx.x;
  if (t < DD) {
    size_t o = (size_t)ids[b] * KP1 + t;
    out[(size_t)b * 600 + t] = (float)enthi[o] + (float)entlo[o];
  }
}

__global__ __launch_bounds__(256) void rownorm_kernel(const float* __restrict__ rows,
                                                      f16* __restrict__ outhi,
                                                      f16* __restrict__ outlo) {
  int b = blockIdx.x;
  int t = threadIdx.x;
  const float* rp = rows + (size_t)b * 600;
  float s = 0.f;
  for (int c = t; c < 600; c += 256) { float v = rp[c]; s += v * v; }
  __shared__ float red[256];
  red[t] = s;
  __syncthreads();
  for (int off = 128; off; off >>= 1) {
    if (t < off) red[t] += red[t + off];
    __syncthreads();
  }
  __shared__ float inv;
  if (t == 0) inv = 1.f / fmaxf(sqrtf(red[0]), 1e-8f);
  __syncthreads();
  for (int c = t; c < KP2; c += 256) {
    float v = (c < 600) ? rp[c] * inv : 0.f;
    f16 hb, lb; split2h(v, hb, lb);
    outhi[(size_t)b * KP2 + c] = hb;
    outlo[(size_t)b * KP2 + c] = lb;
  }
}

__global__ void finalize_kernel(const double* __restrict__ accum, float* __restrict__ out) {
  double neg = accum[0] / ((double)BB * (double)BB);
  double pos = accum[1] / (double)BB;
  out[0] = (float)(neg - 0.2 - pos + 0.9);
}

// ---------------------------------------------------------------------------
static inline void launch_mfma(hipStream_t st, const f16* Ahi, const f16* Alo, int lda,
                               const f16* Bhi, const f16* Blo, int ldb, int M, int Nn, int K,
                               const int* g1, float* C, int ldc, int coloff, const float* bias,
                               int dorelu, const int* rowmask, f16* Chi, f16* Clo, int ldc16,
                               int npass = 3, int wofuse = 0, int losfuse = 0,
                               double* accum = nullptr) {
  dim3 grid((Nn + 127) / 128, (M + 127) / 128);
  mfma_gemm_kernel<<<grid, 256, 0, st>>>(Ahi, Alo, lda, Bhi, Blo, ldb, M, Nn, K, g1, C, ldc,
                                         coloff, bias, dorelu, rowmask, Chi, Clo, ldc16, npass,
                                         wofuse, losfuse, accum);
}

static inline void launch_transpose(hipStream_t st, const float* in, int insz, f16* oh, f16* ol,
                                    int outsz, int Kreal, int Nn, int Kpad, int z) {
  dim3 grid((Kpad + 31) / 32, (Nn + 31) / 32, z);
  transpose_split_kernel<<<grid, 256, 0, st>>>(in, insz, oh, ol, outsz, Kreal, Nn, Kpad);
}

extern "C" void kernel_launch(void* const* d_in, const int* in_sizes, int n_in,
                              void* d_out, int out_size, void* d_ws, size_t ws_size,
                              hipStream_t stream) {
  const float* e_x    = (const float*)d_in[0];
  const float* r_x    = (const float*)d_in[1];
  const float* edge_w = (const float*)d_in[2];
  const float* Wrel   = (const float*)d_in[3];
  const float* brel   = (const float*)d_in[4];
  const float* W1     = (const float*)d_in[5];
  const float* b1     = (const float*)d_in[6];
  const float* W2     = (const float*)d_in[7];
  const float* b2     = (const float*)d_in[8];
  const float* Wprox  = (const float*)d_in[9];
  const float* bprox  = (const float*)d_in[10];
  const float* Wq     = (const float*)d_in[11];
  const float* Wk     = (const float*)d_in[12];
  const float* Wv     = (const float*)d_in[13];
  const float* Wo     = (const float*)d_in[14];
  const int* edge_src = (const int*)d_in[15];
  const int* edge_dst = (const int*)d_in[16];
  const int* l_ids    = (const int*)d_in[17];
  const int* r_ids    = (const int*)d_in[18];
  float* out = (float*)d_out;

  // ---- workspace ----
  char* base = (char*)d_ws;
  size_t off = 0;
  auto nxt = [&](size_t bytes) -> char* {
    char* p = base + off;
    off += (bytes + 63) & ~(size_t)63;
    return p;
  };
  char* R0 = nxt(64512000);   // x fp32 (60.5MB) -> h2 f16 hi+lo (NTOT*KP1 each)
  char* R1 = nxt(64512000);   // agg f16 hi+lo -> kv fp32 (spans into R2)
  char* R2 = nxt(60480000);   // h1 fp32 -> kv tail
  float* qAll  = (float*)nxt(8388608);   // 4096 x 512 fp32
  f16* ctxAhi = (f16*)nxt(4194304);      // 4 x BB x 256
  f16* ctxAlo = (f16*)nxt(4194304);
  f16* emAhi  = (f16*)nxt(4980736);      // 4096 x KP2
  f16* emAlo  = (f16*)nxt(4980736);
  f16* lnhi   = (f16*)nxt(2490368);      // BB x KP2
  f16* lnlo   = (f16*)nxt(2490368);
  f16* rnhi   = (f16*)nxt(2490368);
  f16* rnlo   = (f16*)nxt(2490368);
  f16* qkvhi  = (f16*)nxt(983040);       // 6 x [256 x KP1]: q0,q1,k0,v0,k1,v1
  f16* qkvlo  = (f16*)nxt(983040);
  f16* w12hi  = (f16*)nxt(384000);       // 2 x [300 x KP1]
  f16* w12lo  = (f16*)nxt(384000);
  f16* wohi   = (f16*)nxt(307200);       // [600 x 256]
  f16* wolo   = (f16*)nxt(307200);
  f16* wpxhi  = (f16*)nxt(364800);       // [300 x KP2]
  f16* wpxlo  = (f16*)nxt(364800);
  double* accum = (double*)nxt(16);
  int* row_ptr  = (int*)nxt(4 * (NTOT + 1));
  int* cursor   = (int*)nxt(4 * NTOT);
  int* counts   = (int*)nxt(4 * NTOT);
  int* src_s    = (int*)nxt(4 * EE);
  float* w_s    = (float*)nxt(4 * EE);
  int* mask_norm = (int*)nxt(4 * 4 * BB * LL);
  int* maskany   = (int*)nxt(4 * 4 * BB);
  int* idsAll    = (int*)nxt(4 * 2 * BB);
  int* flag      = (int*)nxt(64);

  float* xbuf = (float*)R0;
  f16* h2hi = (f16*)R0;  f16* h2lo = h2hi + (size_t)NTOT * KP1;
  f16* agghi = (f16*)R1; f16* agglo = agghi + (size_t)NTOT * KP1;
  float* kvbuf = (float*)R1;   // NTOT x 512 fp32 = 103 MB, spans R1+R2
  float* h1 = (float*)R2;

  hipMemsetAsync(counts, 0, NTOT * sizeof(int), stream);
  hipMemsetAsync(maskany, 0, 4 * BB * sizeof(int), stream);
  hipMemsetAsync(flag, 0, sizeof(int), stream);
  hipMemsetAsync(accum, 0, 2 * sizeof(double), stream);

  // x = [e_x ; r_x @ Wrel + brel]
  copy_f4_kernel<<<(3750000 + 255) / 256, 256, 0, stream>>>((const float4*)e_x, (float4*)xbuf,
                                                            3750000);
  rel_proj_kernel<<<NR, 320, 0, stream>>>(r_x, Wrel, brel, xbuf + (size_t)NE * DD);

  // CSR
  hist_kernel<<<(EE + 255) / 256, 256, 0, stream>>>(edge_dst, counts);
  scan_kernel<<<1, 1024, 0, stream>>>(counts, row_ptr, cursor);
  scatter_kernel<<<(EE + 255) / 256, 256, 0, stream>>>(edge_dst, edge_src, edge_w, cursor, src_s,
                                                       w_s);

  // masks + ids
  detect_mask_kernel<<<256, 256, 0, stream>>>((const unsigned*)d_in[21], (const unsigned*)d_in[24],
                                              (const unsigned*)d_in[27], (const unsigned*)d_in[30],
                                              flag);
  for (int mi = 0; mi < 4; ++mi)
    norm_mask_kernel<<<(BB * LL + 255) / 256, 256, 0, stream>>>(
        d_in[21 + mi * 3], mask_norm + (size_t)mi * BB * LL, maskany + mi * BB, flag);
  concat_ids_kernel<<<(2 * BB + 255) / 256, 256, 0, stream>>>(l_ids, r_ids, idsAll);

  // weight transposes (coalesced LDS-tiled); qkv layout q0,q1,k0,v0,k1,v1
  launch_transpose(stream, Wq, 300 * 256, qkvhi + 0 * 81920, qkvlo + 0 * 81920, 81920, 300, 256,
                   KP1, 2);
  launch_transpose(stream, Wk, 0, qkvhi + 2 * 81920, qkvlo + 2 * 81920, 81920, 300, 256, KP1, 1);
  launch_transpose(stream, Wv, 0, qkvhi + 3 * 81920, qkvlo + 3 * 81920, 81920, 300, 256, KP1, 1);
  launch_transpose(stream, Wk + 300 * 256, 0, qkvhi + 4 * 81920, qkvlo + 4 * 81920, 81920, 300,
                   256, KP1, 1);
  launch_transpose(stream, Wv + 300 * 256, 0, qkvhi + 5 * 81920, qkvlo + 5 * 81920, 81920, 300,
                   256, KP1, 1);
  launch_transpose(stream, W1, 0, w12hi, w12lo, 96000, 300, 300, KP1, 1);
  launch_transpose(stream, W2, 0, w12hi + 96000, w12lo + 96000, 96000, 300, 300, KP1, 1);
  launch_transpose(stream, Wo, 256 * 300, wohi, wolo, 76800, 256, 300, 256, 2);
  launch_transpose(stream, Wprox, 0, wpxhi, wpxlo, 182400, 600, 300, KP2, 1);

  // K-pad zeroing
  pad_zero_kernel<<<(NTOT * 20 + 255) / 256, 256, 0, stream>>>(agghi, agglo, NTOT, KP1, 300);
  pad_zero_kernel<<<(4096 * 8 + 255) / 256, 256, 0, stream>>>(emAhi, emAlo, 4096, KP2, 600);

  // GCN
  aggregate_kernel<<<NTOT, 320, 0, stream>>>(xbuf, agghi, agglo, row_ptr, src_s, w_s);
  launch_mfma(stream, agghi, agglo, KP1, w12hi, w12lo, KP1, NTOT, 300, KP1, nullptr, h1, 300, 0,
              b1, 1, nullptr, nullptr, nullptr, 0, 2);
  aggregate_kernel<<<NTOT, 320, 0, stream>>>(h1, agghi, agglo, row_ptr, src_s, w_s);
  pad_zero_kernel<<<(NTOT * 20 + 255) / 256, 256, 0, stream>>>(h2hi, h2lo, NTOT, KP1, 300);
  launch_mfma(stream, agghi, agglo, KP1, w12hi + 96000, w12lo + 96000, KP1, NTOT, 300, KP1,
              nullptr, nullptr, 0, 0, b2, 0, nullptr, h2hi, h2lo, KP1, 3);

  // q (single batched GEMM, M=4096, N=512: dirs 0|1)
  launch_mfma(stream, h2hi, h2lo, KP1, qkvhi, qkvlo, KP1, 2 * BB, 512, KP1, idsAll, qAll, 512, 0,
              nullptr, 0, nullptr, nullptr, nullptr, 0, 2);

  // encoders: fused kv per dir, attention fused over sides
  for (int dir = 0; dir < 2; ++dir) {
    launch_mfma(stream, h2hi, h2lo, KP1, qkvhi + (2 + 2 * dir) * 81920,
                qkvlo + (2 + 2 * dir) * 81920, KP1, NTOT, 512, KP1, nullptr, kvbuf, 512, 0,
                nullptr, 0, nullptr, nullptr, nullptr, 0, 2);
    attention_kernel<<<dim3(BB, 2), 256, 0, stream>>>(
        qAll, kvbuf,
        (const int*)d_in[20 + dir * 3], (const int*)d_in[19 + dir * 3],
        mask_norm + (size_t)(0 * 2 + dir) * BB * LL,
        (const int*)d_in[26 + dir * 3], (const int*)d_in[25 + dir * 3],
        mask_norm + (size_t)(1 * 2 + dir) * BB * LL,
        dir * 256, ctxAhi + (size_t)dir * 2 * BB * 256, ctxAlo + (size_t)dir * 2 * BB * 256);
  }

  // Wo (batched): M=8192 over ctxAll, epilogue routes into emAll
  launch_mfma(stream, ctxAhi, ctxAlo, 256, wohi, wolo, 256, 4 * BB, 600, 256, nullptr, nullptr,
              0, 0, nullptr, 0, maskany, emAhi, emAlo, KP2, 3, 1);

  // proximity (batched M=4096: lem rows then rem rows — contiguous in d_out)
  float* lem = out + 1;
  float* rem = out + 1 + (size_t)BB * 600;
  launch_mfma(stream, emAhi, emAlo, KP2, wpxhi, wpxlo, KP2, 4096, 300, KP2, nullptr, lem, 600,
              300, bprox, 0, nullptr, nullptr, nullptr, 0, 3);
  gather_part_kernel<<<BB, 320, 0, stream>>>(h2hi, h2lo, l_ids, lem);
  gather_part_kernel<<<BB, 320, 0, stream>>>(h2hi, h2lo, r_ids, rem);

  // cosine similarity + fused loss
  rownorm_kernel<<<BB, 256, 0, stream>>>(lem, lnhi, lnlo);
  rownorm_kernel<<<BB, 256, 0, stream>>>(rem, rnhi, rnlo);
  launch_mfma(stream, lnhi, lnlo, KP2, rnhi, rnlo, KP2, BB, BB, KP2, nullptr, nullptr, 0, 0,
              nullptr, 0, nullptr, nullptr, nullptr, 0, 1, 0, 1, accum);
  finalize_kernel<<<1, 1, 0, stream>>>(accum, out);
}

// Round 7
// 1174.404 us; speedup vs baseline: 3.1256x; 1.1994x over previous
//
#include <hip/hip_runtime.h>
#include <cstdint>
#include <cstddef>

typedef _Float16 f16;
typedef __attribute__((ext_vector_type(8))) _Float16 half8;
typedef __attribute__((ext_vector_type(4))) _Float16 half4;
typedef __attribute__((ext_vector_type(4))) float f32x4;

#define NE 50000
#define NR 400
#define DD 300
#define NTOT 50400
#define EE 800000
#define BB 2048
#define LL 32
#define HD 256
#define KP1 320
#define KP2 608

// split fp32 into fp16 hi + fp16 lo (22-bit combined mantissa)
__device__ inline void split2h(float x, f16& hi, f16& lo) {
  f16 h = (f16)x;
  hi = h;
  lo = (f16)(x - (float)h);
}

// ---------------------------------------------------------------------------
__global__ void convert_f16_kernel(const float4* __restrict__ src, half4* __restrict__ dst,
                                   int n4) {
  int i = blockIdx.x * blockDim.x + threadIdx.x;
  if (i < n4) {
    float4 v = src[i];
    dst[i] = (half4){(f16)v.x, (f16)v.y, (f16)v.z, (f16)v.w};
  }
}

__global__ void rel_proj_kernel(const float* __restrict__ r_x, const float* __restrict__ Wrel,
                                const float* __restrict__ brel, f16* __restrict__ out) {
  int row = blockIdx.x;
  int c = threadIdx.x;
  if (c >= DD) return;
  float acc = brel[c];
  const float* rr = r_x + (size_t)row * (2 * DD);
  for (int k = 0; k < 2 * DD; ++k) acc += rr[k] * Wrel[(size_t)k * DD + c];
  out[(size_t)row * DD + c] = (f16)acc;
}

__global__ void hist_kernel(const int* __restrict__ dst, int* __restrict__ counts) {
  int e = blockIdx.x * blockDim.x + threadIdx.x;
  if (e < EE) atomicAdd(&counts[dst[e]], 1);
}

__global__ __launch_bounds__(1024) void scan_kernel(const int* __restrict__ counts,
                                                    int* __restrict__ row_ptr,
                                                    int* __restrict__ cursor) {
  __shared__ int sums[1024];
  const int n = NTOT;
  int t = threadIdx.x;
  const int chunk = (n + 1023) / 1024;
  int begin = t * chunk;
  int end = begin + chunk; if (end > n) end = n;
  int s = 0;
  for (int i = begin; i < end; ++i) s += counts[i];
  sums[t] = s;
  __syncthreads();
  for (int off = 1; off < 1024; off <<= 1) {
    int v = (t >= off) ? sums[t - off] : 0;
    __syncthreads();
    sums[t] += v;
    __syncthreads();
  }
  int run = sums[t] - s;
  for (int i = begin; i < end; ++i) {
    row_ptr[i] = run; cursor[i] = run;
    run += counts[i];
  }
  if (t == 1023) row_ptr[n] = sums[1023];
}

__global__ void scatter_kernel(const int* __restrict__ dst, const int* __restrict__ src,
                               const float* __restrict__ w, int* __restrict__ cursor,
                               int* __restrict__ src_s, float* __restrict__ w_s) {
  int e = blockIdx.x * blockDim.x + threadIdx.x;
  if (e < EE) {
    int pos = atomicAdd(&cursor[dst[e]], 1);
    src_s[pos] = src[e];
    w_s[pos] = w[e];
  }
}

__global__ void detect_mask_kernel(const unsigned* __restrict__ m0, const unsigned* __restrict__ m1,
                                   const unsigned* __restrict__ m2, const unsigned* __restrict__ m3,
                                   int* __restrict__ flag) {
  int idx = blockIdx.x * blockDim.x + threadIdx.x;
  const int wp = BB * LL / 4;
  if (idx >= 4 * wp) return;
  const unsigned* p = idx < wp ? m0 : idx < 2 * wp ? m1 : idx < 3 * wp ? m2 : m3;
  if (p[idx % wp] > 1u) atomicOr(flag, 1);
}

// all 4 masks in one launch; outm index = mi*BB*LL + k, many index = mi*BB + b
__global__ void norm_mask4_kernel(const void* __restrict__ r0, const void* __restrict__ r1,
                                  const void* __restrict__ r2, const void* __restrict__ r3,
                                  int* __restrict__ outm, int* __restrict__ many,
                                  const int* __restrict__ flag) {
  int idx = blockIdx.x * blockDim.x + threadIdx.x;
  if (idx >= 4 * BB * LL) return;
  int mi = idx / (BB * LL), k = idx % (BB * LL);
  const void* raw = mi == 0 ? r0 : mi == 1 ? r1 : mi == 2 ? r2 : r3;
  int v = (*flag) ? (int)((const unsigned char*)raw)[k] : ((const int*)raw)[k];
  v = v ? 1 : 0;
  outm[idx] = v;
  if (v) atomicOr(&many[idx >> 5], 1);
}

__global__ void concat_ids_kernel(const int* __restrict__ a, const int* __restrict__ b,
                                  int* __restrict__ o) {
  int i = blockIdx.x * blockDim.x + threadIdx.x;
  if (i < BB) o[i] = a[i];
  else if (i < 2 * BB) o[i] = b[i - BB];
}

// aggregate: gathers f16 features (half traffic), fp32 accumulate, split hi/lo out
__global__ __launch_bounds__(320) void aggregate_kernel(
    const f16* __restrict__ feat, f16* __restrict__ outhi, f16* __restrict__ outlo,
    const int* __restrict__ row_ptr, const int* __restrict__ srcs, const float* __restrict__ ws) {
  int d = blockIdx.x;
  int f = threadIdx.x;
  if (f >= DD) return;
  int beg = row_ptr[d], end = row_ptr[d + 1];
  float acc = 0.f;
  int e = beg;
  for (; e + 8 <= end; e += 8) {
    int s[8]; float wv[8]; float v[8];
#pragma unroll
    for (int u = 0; u < 8; ++u) { s[u] = srcs[e + u]; wv[u] = ws[e + u]; }
#pragma unroll
    for (int u = 0; u < 8; ++u) v[u] = (float)feat[(size_t)s[u] * DD + f];
#pragma unroll
    for (int u = 0; u < 8; ++u) acc += wv[u] * v[u];
  }
  for (; e + 2 <= end; e += 2) {
    int s0 = srcs[e], s1 = srcs[e + 1];
    float w0 = ws[e], w1 = ws[e + 1];
    acc += w0 * (float)feat[(size_t)s0 * DD + f] + w1 * (float)feat[(size_t)s1 * DD + f];
  }
  if (e < end) acc += ws[e] * (float)feat[(size_t)srcs[e] * DD + f];
  f16 hi, lo; split2h(acc, hi, lo);
  outhi[(size_t)d * KP1 + f] = hi;
  outlo[(size_t)d * KP1 + f] = lo;
}

__global__ void pad_zero_kernel(f16* __restrict__ hi, f16* __restrict__ lo, int rows, int ld, int c0) {
  int pw = ld - c0;
  int idx = blockIdx.x * blockDim.x + threadIdx.x;
  if (idx >= rows * pw) return;
  int r = idx / pw, c = c0 + idx % pw;
  hi[(size_t)r * ld + c] = (f16)0.f;
  if (lo) lo[(size_t)r * ld + c] = (f16)0.f;
}

// ---- combined weight transpose+split: all matrices, one dispatch ----------
#define N_TD 11
struct TDesc {
  const float* in; f16* oh; f16* ol;
  int Kreal, Nn, Kpad, tiles_x, tile_base;
};
struct TPack { TDesc d[N_TD]; };

__global__ __launch_bounds__(256) void transpose_multi_kernel(TPack p) {
  __shared__ float tile[32][33];
  int t = blockIdx.x;
  int e = 0;
#pragma unroll
  for (int i = 1; i < N_TD; ++i)
    if (t >= p.d[i].tile_base) e = i;
  TDesc dd = p.d[e];
  int local = t - dd.tile_base;
  int k0 = (local % dd.tiles_x) * 32, n0 = (local / dd.tiles_x) * 32;
  int tx = threadIdx.x & 31, ty = threadIdx.x >> 5;
#pragma unroll
  for (int r = 0; r < 4; ++r) {
    int k = k0 + ty + r * 8, n = n0 + tx;
    float v = (k < dd.Kreal && n < dd.Nn) ? dd.in[(size_t)k * dd.Nn + n] : 0.f;
    tile[ty + r * 8][tx] = v;
  }
  __syncthreads();
#pragma unroll
  for (int r = 0; r < 4; ++r) {
    int n = n0 + ty + r * 8, k = k0 + tx;
    if (n < dd.Nn && k < dd.Kpad) {
      f16 h, l; split2h(tile[tx][ty + r * 8], h, l);
      dd.oh[(size_t)n * dd.Kpad + k] = h;
      dd.ol[(size_t)n * dd.Kpad + k] = l;
    }
  }
}

// ---------------------------------------------------------------------------
// split-fp16 MFMA GEMM: C = gather(A) @ B^T
//   npass=1: ah*bh ; npass=2: + al*bh (rel ~2^-12) ; npass=3: + ah*bl (rel ~2^-22)
// wofuse: route into emAll[4096 x KP2] cols dir*300..+300 (chunks of 2048 rows)
// losfuse: fused clamped-mean loss reduction
// Chi with Clo==nullptr: write single f16
// ---------------------------------------------------------------------------
__global__ __launch_bounds__(256, 2) void mfma_gemm_kernel(
    const f16* __restrict__ Ahi, const f16* __restrict__ Alo, int lda,
    const f16* __restrict__ Bhi, const f16* __restrict__ Blo, int ldb,
    int M, int Nn, int K, const int* __restrict__ g1,
    float* __restrict__ C, int ldc, int coloff,
    const float* __restrict__ bias, int dorelu, const int* __restrict__ rowmask,
    f16* __restrict__ Chi, f16* __restrict__ Clo, int ldc16,
    int npass, int wofuse, int losfuse, double* __restrict__ accum) {
  __shared__ int4 sAh[512], sAl[512], sBh[512], sBl[512];
  const int tid = threadIdx.x;
  const int row0 = blockIdx.y * 128, col0 = blockIdx.x * 128;
  const int wave = tid >> 6, lane = tid & 63;
  const int wrow = (wave >> 1) * 64, wcol = (wave & 1) * 64;
  const int m16 = lane & 15, quad = lane >> 4;

  const int sr = tid >> 2, sc = tid & 3;
  const f16* pah[2]; const f16* pal[2]; bool va[2];
  const f16* pbh[2]; const f16* pbl[2]; bool vb[2];
  int sidx[2];
#pragma unroll
  for (int i = 0; i < 2; ++i) {
    int r = sr + i * 64;
    sidx[i] = r * 4 + (sc ^ ((r >> 1) & 3));
    int grow = row0 + r;
    va[i] = grow < M;
    int ar = va[i] ? (g1 ? g1[grow] : grow) : 0;
    pah[i] = Ahi + (size_t)ar * lda + sc * 8;
    pal[i] = Alo + (size_t)ar * lda + sc * 8;
    int gn = col0 + r;
    vb[i] = gn < Nn;
    int br = vb[i] ? gn : 0;
    pbh[i] = Bhi + (size_t)br * ldb + sc * 8;
    pbl[i] = Blo + (size_t)br * ldb + sc * 8;
  }
  int idxA[4], idxB[4];
#pragma unroll
  for (int f = 0; f < 4; ++f) {
    int r = wrow + f * 16 + m16;
    idxA[f] = r * 4 + (quad ^ ((r >> 1) & 3));
    int n = wcol + f * 16 + m16;
    idxB[f] = n * 4 + (quad ^ ((n >> 1) & 3));
  }
  f32x4 acc[4][4];
#pragma unroll
  for (int i = 0; i < 4; ++i)
#pragma unroll
    for (int j = 0; j < 4; ++j) acc[i][j] = (f32x4){0.f, 0.f, 0.f, 0.f};

  const int4 z4 = {0, 0, 0, 0};
  for (int k0 = 0; k0 < K; k0 += 32) {
#pragma unroll
    for (int i = 0; i < 2; ++i) {
      int4 vh = z4, wh = z4;
      if (va[i]) vh = *(const int4*)(pah[i] + k0);
      if (vb[i]) wh = *(const int4*)(pbh[i] + k0);
      sAh[sidx[i]] = vh; sBh[sidx[i]] = wh;
      if (npass >= 2) {
        int4 vl = z4;
        if (va[i]) vl = *(const int4*)(pal[i] + k0);
        sAl[sidx[i]] = vl;
      }
      if (npass >= 3) {
        int4 wl = z4;
        if (vb[i]) wl = *(const int4*)(pbl[i] + k0);
        sBl[sidx[i]] = wl;
      }
    }
    __syncthreads();
    half8 ah[4], bh[4];
#pragma unroll
    for (int f = 0; f < 4; ++f) {
      ah[f] = *(const half8*)&sAh[idxA[f]];
      bh[f] = *(const half8*)&sBh[idxB[f]];
    }
#pragma unroll
    for (int i = 0; i < 4; ++i)
#pragma unroll
      for (int j = 0; j < 4; ++j)
        acc[i][j] = __builtin_amdgcn_mfma_f32_16x16x32_f16(ah[i], bh[j], acc[i][j], 0, 0, 0);
    if (npass >= 2) {
      half8 al[4];
#pragma unroll
      for (int f = 0; f < 4; ++f) al[f] = *(const half8*)&sAl[idxA[f]];
#pragma unroll
      for (int i = 0; i < 4; ++i)
#pragma unroll
        for (int j = 0; j < 4; ++j)
          acc[i][j] = __builtin_amdgcn_mfma_f32_16x16x32_f16(al[i], bh[j], acc[i][j], 0, 0, 0);
    }
    if (npass >= 3) {
      half8 bl[4];
#pragma unroll
      for (int f = 0; f < 4; ++f) bl[f] = *(const half8*)&sBl[idxB[f]];
#pragma unroll
      for (int i = 0; i < 4; ++i)
#pragma unroll
        for (int j = 0; j < 4; ++j)
          acc[i][j] = __builtin_amdgcn_mfma_f32_16x16x32_f16(ah[i], bl[j], acc[i][j], 0, 0, 0);
    }
    __syncthreads();
  }

  if (losfuse) {
    float negs = 0.f, poss = 0.f;
#pragma unroll
    for (int i = 0; i < 4; ++i)
#pragma unroll
      for (int reg = 0; reg < 4; ++reg) {
        int row = row0 + wrow + i * 16 + quad * 4 + reg;
#pragma unroll
        for (int j = 0; j < 4; ++j) {
          int col = col0 + wcol + j * 16 + m16;
          float s = acc[i][j][reg];
          if (row == col) { negs += 0.2f; poss += fminf(s, 0.9f); }
          else negs += fmaxf(s, 0.2f);
        }
      }
    float* rn_ = (float*)sAh;
    float* rp_ = (float*)sAl;
    rn_[tid] = negs; rp_[tid] = poss;
    __syncthreads();
    for (int off2 = 128; off2; off2 >>= 1) {
      if (tid < off2) { rn_[tid] += rn_[tid + off2]; rp_[tid] += rp_[tid + off2]; }
      __syncthreads();
    }
    if (tid == 0) {
      atomicAdd(&accum[0], (double)rn_[0]);
      atomicAdd(&accum[1], (double)rp_[0]);
    }
    return;
  }

#pragma unroll
  for (int i = 0; i < 4; ++i) {
#pragma unroll
    for (int reg = 0; reg < 4; ++reg) {
      int row = row0 + wrow + i * 16 + quad * 4 + reg;
      if (row >= M) continue;
      if (wofuse) {
        int b = row & 2047, side = (row >> 11) & 1, dir = (row >> 12) & 1;
        bool zero = rowmask[(side * 2 + dir) * BB + b] == 0;
        int orow = side * 2048 + b;
#pragma unroll
        for (int j = 0; j < 4; ++j) {
          int col = col0 + wcol + j * 16 + m16;
          if (col >= Nn) continue;
          if ((col >= 300) != (dir != 0)) continue;
          float v = acc[i][j][reg];
          if (zero) v = 0.f;
          f16 hb, lb; split2h(v, hb, lb);
          Chi[(size_t)orow * ldc16 + col] = hb;
          Clo[(size_t)orow * ldc16 + col] = lb;
        }
        continue;
      }
      bool zero = (rowmask != nullptr) && (rowmask[row] == 0);
#pragma unroll
      for (int j = 0; j < 4; ++j) {
        int col = col0 + wcol + j * 16 + m16;
        if (col >= Nn) continue;
        float v = acc[i][j][reg];
        if (bias) v += bias[col];
        if (dorelu) v = fmaxf(v, 0.f);
        if (zero) v = 0.f;
        if (C) C[(size_t)row * ldc + coloff + col] = v;
        if (Chi) {
          f16 hb, lb; split2h(v, hb, lb);
          Chi[(size_t)row * ldc16 + coloff + col] = hb;
          if (Clo) Clo[(size_t)row * ldc16 + coloff + col] = lb;
        }
      }
    }
  }
}

// ---------------------------------------------------------------------------
// attention over f16 kvAll[row][1024] = [k0|v0|k1|v1]; grid (BB, 4), y = dir*2+side
__global__ __launch_bounds__(256) void attention_kernel(
    const float* __restrict__ qAll, const f16* __restrict__ kv,
    const int* __restrict__ h00, const int* __restrict__ r00,   // side0 dir0 (l_in)
    const int* __restrict__ h01, const int* __restrict__ r01,   // side0 dir1 (l_out)
    const int* __restrict__ h10, const int* __restrict__ r10,   // side1 dir0 (r_in)
    const int* __restrict__ h11, const int* __restrict__ r11,   // side1 dir1 (r_out)
    const int* __restrict__ mask_norm, f16* __restrict__ ctxhi, f16* __restrict__ ctxlo) {
  int b = blockIdx.x;
  int y = blockIdx.y;
  int dir = y >> 1, side = y & 1;
  int tid = threadIdx.x;
  const int* hs = side ? (dir ? h11 : h10) : (dir ? h01 : h00);
  const int* rs = side ? (dir ? r11 : r10) : (dir ? r01 : r00);
  const int* msk = mask_norm + (size_t)(side * 2 + dir) * BB * LL;
  __shared__ float qs[256];
  __shared__ float attns[8][33];
  __shared__ int hid[32], rid[32], ms[32];
  qs[tid] = qAll[((size_t)(side * BB + b)) * 512 + dir * 256 + tid];
  if (tid < 32) {
    hid[tid] = hs[b * LL + tid];
    rid[tid] = NE + rs[b * LL + tid];
    ms[tid] = msk[b * LL + tid];
  }
  __syncthreads();
  int h = tid >> 5, l = tid & 31;
  const half8* k1 = (const half8*)(kv + (size_t)hid[l] * 1024 + dir * 512 + h * 32);
  const half8* k2 = (const half8*)(kv + (size_t)rid[l] * 1024 + dir * 512 + h * 32);
  float s = 0.f;
#pragma unroll
  for (int i = 0; i < 4; ++i) {
    half8 a = k1[i], c8 = k2[i];
    const float* qp = &qs[h * 32 + i * 8];
#pragma unroll
    for (int j = 0; j < 8; ++j) s += qp[j] * ((float)a[j] + (float)c8[j]);
  }
  s *= 0.17677669529663687f;
  s = ms[l] ? s : -1e9f;
  float m = s;
  for (int off = 16; off; off >>= 1) m = fmaxf(m, __shfl_xor(m, off, 32));
  float e = expf(s - m);
  float sum = e;
  for (int off = 16; off; off >>= 1) sum += __shfl_xor(sum, off, 32);
  attns[h][l] = e / sum;
  __syncthreads();
  int d = tid & 31;
  float c = 0.f;
#pragma unroll 4
  for (int l2 = 0; l2 < 32; ++l2) {
    float a = attns[h][l2];
    float v = (float)kv[(size_t)hid[l2] * 1024 + dir * 512 + 256 + h * 32 + d] +
              (float)kv[(size_t)rid[l2] * 1024 + dir * 512 + 256 + h * 32 + d];
    c += a * v;
  }
  f16 hb, lb; split2h(c, hb, lb);
  size_t o = ((size_t)(dir * 2 + side) * BB + b) * 256 + tid;
  ctxhi[o] = hb;
  ctxlo[o] = lb;
}

__global__ void gather_part_kernel(const f16* __restrict__ enthi, const f16* __restrict__ entlo,
                                   const int* __restrict__ ids, float* __restrict__ out) {
  int b = blockIdx.x;
  int t = threadIdx.x;
  if (t < DD) {
    size_t o = (size_t)ids[b] * KP1 + t;
    out[(size_t)b * 600 + t] = (float)enthi[o] + (float)entlo[o];
  }
}

__global__ __launch_bounds__(256) void rownorm_kernel(const float* __restrict__ rows,
                                                      f16* __restrict__ outhi,
                                                      f16* __restrict__ outlo) {
  int b = blockIdx.x;
  int t = threadIdx.x;
  const float* rp = rows + (size_t)b * 600;
  float s = 0.f;
  for (int c = t; c < 600; c += 256) { float v = rp[c]; s += v * v; }
  __shared__ float red[256];
  red[t] = s;
  __syncthreads();
  for (int off = 128; off; off >>= 1) {
    if (t < off) red[t] += red[t + off];
    __syncthreads();
  }
  __shared__ float inv;
  if (t == 0) inv = 1.f / fmaxf(sqrtf(red[0]), 1e-8f);
  __syncthreads();
  for (int c = t; c < KP2; c += 256) {
    float v = (c < 600) ? rp[c] * inv : 0.f;
    f16 hb, lb; split2h(v, hb, lb);
    outhi[(size_t)b * KP2 + c] = hb;
    outlo[(size_t)b * KP2 + c] = lb;
  }
}

__global__ void finalize_kernel(const double* __restrict__ accum, float* __restrict__ out) {
  double neg = accum[0] / ((double)BB * (double)BB);
  double pos = accum[1] / (double)BB;
  out[0] = (float)(neg - 0.2 - pos + 0.9);
}

// ---------------------------------------------------------------------------
static inline void launch_mfma(hipStream_t st, const f16* Ahi, const f16* Alo, int lda,
                               const f16* Bhi, const f16* Blo, int ldb, int M, int Nn, int K,
                               const int* g1, float* C, int ldc, int coloff, const float* bias,
                               int dorelu, const int* rowmask, f16* Chi, f16* Clo, int ldc16,
                               int npass = 3, int wofuse = 0, int losfuse = 0,
                               double* accum = nullptr) {
  dim3 grid((Nn + 127) / 128, (M + 127) / 128);
  mfma_gemm_kernel<<<grid, 256, 0, st>>>(Ahi, Alo, lda, Bhi, Blo, ldb, M, Nn, K, g1, C, ldc,
                                         coloff, bias, dorelu, rowmask, Chi, Clo, ldc16, npass,
                                         wofuse, losfuse, accum);
}

extern "C" void kernel_launch(void* const* d_in, const int* in_sizes, int n_in,
                              void* d_out, int out_size, void* d_ws, size_t ws_size,
                              hipStream_t stream) {
  const float* e_x    = (const float*)d_in[0];
  const float* r_x    = (const float*)d_in[1];
  const float* edge_w = (const float*)d_in[2];
  const float* Wrel   = (const float*)d_in[3];
  const float* brel   = (const float*)d_in[4];
  const float* W1     = (const float*)d_in[5];
  const float* b1     = (const float*)d_in[6];
  const float* W2     = (const float*)d_in[7];
  const float* b2     = (const float*)d_in[8];
  const float* Wprox  = (const float*)d_in[9];
  const float* bprox  = (const float*)d_in[10];
  const float* Wq     = (const float*)d_in[11];
  const float* Wk     = (const float*)d_in[12];
  const float* Wv     = (const float*)d_in[13];
  const float* Wo     = (const float*)d_in[14];
  const int* edge_src = (const int*)d_in[15];
  const int* edge_dst = (const int*)d_in[16];
  const int* l_ids    = (const int*)d_in[17];
  const int* r_ids    = (const int*)d_in[18];
  float* out = (float*)d_out;

  // ---- workspace ----
  char* base = (char*)d_ws;
  size_t off = 0;
  auto nxt = [&](size_t bytes) -> char* {
    char* p = base + off;
    off += (bytes + 63) & ~(size_t)63;
    return p;
  };
  char* R0 = nxt(64512000);   // x f16 (30.2MB) -> h2 f16 hi+lo (NTOT*KP1 each)
  char* R1 = nxt(64512000);   // agg f16 hi+lo -> kvAll f16 (spans into R2)
  char* R2 = nxt(60480000);   // h1 f16 -> kvAll tail
  float* qAll  = (float*)nxt(8388608);   // 4096 x 512 fp32
  f16* ctxAhi = (f16*)nxt(4194304);      // 4 x BB x 256 f16 = 2,097,152 elem = 4 MB (R6 bug: was 2MB)
  f16* ctxAlo = (f16*)nxt(4194304);
  f16* emAhi  = (f16*)nxt(4980736);      // 4096 x KP2
  f16* emAlo  = (f16*)nxt(4980736);
  f16* lnhi   = (f16*)nxt(2490368);      // BB x KP2
  f16* lnlo   = (f16*)nxt(2490368);
  f16* rnhi   = (f16*)nxt(2490368);
  f16* rnlo   = (f16*)nxt(2490368);
  f16* qkvhi  = (f16*)nxt(983040);       // 6 x [256 x KP1]: q0,q1,k0,v0,k1,v1
  f16* qkvlo  = (f16*)nxt(983040);
  f16* w12hi  = (f16*)nxt(384000);       // 2 x [300 x KP1]
  f16* w12lo  = (f16*)nxt(384000);
  f16* wohi   = (f16*)nxt(307200);       // [600 x 256]
  f16* wolo   = (f16*)nxt(307200);
  f16* wpxhi  = (f16*)nxt(364800);       // [300 x KP2]
  f16* wpxlo  = (f16*)nxt(364800);
  double* accum = (double*)nxt(16);
  int* row_ptr  = (int*)nxt(4 * (NTOT + 1));
  int* cursor   = (int*)nxt(4 * NTOT);
  int* counts   = (int*)nxt(4 * NTOT);
  int* src_s    = (int*)nxt(4 * EE);
  float* w_s    = (float*)nxt(4 * EE);
  int* mask_norm = (int*)nxt(4 * 4 * BB * LL);
  int* maskany   = (int*)nxt(4 * 4 * BB);
  int* idsAll    = (int*)nxt(4 * 2 * BB);
  int* flag      = (int*)nxt(64);

  f16* xbuf16 = (f16*)R0;                 // NTOT x DD
  f16* h2hi = (f16*)R0;  f16* h2lo = h2hi + (size_t)NTOT * KP1;
  f16* agghi = (f16*)R1; f16* agglo = agghi + (size_t)NTOT * KP1;
  f16* kvAll = (f16*)R1;                  // NTOT x 1024 f16 = 103 MB, spans R1+R2
  f16* h1f16 = (f16*)R2;                  // NTOT x DD

  hipMemsetAsync(counts, 0, NTOT * sizeof(int), stream);
  hipMemsetAsync(maskany, 0, 4 * BB * sizeof(int), stream);
  hipMemsetAsync(flag, 0, sizeof(int), stream);
  hipMemsetAsync(accum, 0, 2 * sizeof(double), stream);

  // x (f16) = [e_x ; r_x @ Wrel + brel]
  convert_f16_kernel<<<(3750000 + 255) / 256, 256, 0, stream>>>((const float4*)e_x,
                                                                (half4*)xbuf16, 3750000);
  rel_proj_kernel<<<NR, 320, 0, stream>>>(r_x, Wrel, brel, xbuf16 + (size_t)NE * DD);

  // CSR
  hist_kernel<<<(EE + 255) / 256, 256, 0, stream>>>(edge_dst, counts);
  scan_kernel<<<1, 1024, 0, stream>>>(counts, row_ptr, cursor);
  scatter_kernel<<<(EE + 255) / 256, 256, 0, stream>>>(edge_dst, edge_src, edge_w, cursor, src_s,
                                                       w_s);

  // masks + ids
  detect_mask_kernel<<<256, 256, 0, stream>>>((const unsigned*)d_in[21], (const unsigned*)d_in[24],
                                              (const unsigned*)d_in[27], (const unsigned*)d_in[30],
                                              flag);
  norm_mask4_kernel<<<(4 * BB * LL + 255) / 256, 256, 0, stream>>>(
      d_in[21], d_in[24], d_in[27], d_in[30], mask_norm, maskany, flag);
  concat_ids_kernel<<<(2 * BB + 255) / 256, 256, 0, stream>>>(l_ids, r_ids, idsAll);

  // all weight transposes, one dispatch
  {
    TPack p;
    int tb = 0, idx = 0;
    auto add = [&](const float* in, f16* oh, f16* ol, int Kreal, int Nn, int Kpad) {
      int txs = (Kpad + 31) / 32, tys = (Nn + 31) / 32;
      p.d[idx] = TDesc{in, oh, ol, Kreal, Nn, Kpad, txs, tb};
      tb += txs * tys;
      ++idx;
    };
    add(Wq,             qkvhi + 0 * 81920, qkvlo + 0 * 81920, 300, 256, KP1);
    add(Wq + 300 * 256, qkvhi + 1 * 81920, qkvlo + 1 * 81920, 300, 256, KP1);
    add(Wk,             qkvhi + 2 * 81920, qkvlo + 2 * 81920, 300, 256, KP1);
    add(Wv,             qkvhi + 3 * 81920, qkvlo + 3 * 81920, 300, 256, KP1);
    add(Wk + 300 * 256, qkvhi + 4 * 81920, qkvlo + 4 * 81920, 300, 256, KP1);
    add(Wv + 300 * 256, qkvhi + 5 * 81920, qkvlo + 5 * 81920, 300, 256, KP1);
    add(W1,             w12hi,             w12lo,             300, 300, KP1);
    add(W2,             w12hi + 96000,     w12lo + 96000,     300, 300, KP1);
    add(Wo,             wohi,              wolo,              256, 300, 256);
    add(Wo + 256 * 300, wohi + 76800,      wolo + 76800,      256, 300, 256);
    add(Wprox,          wpxhi,             wpxlo,             600, 300, KP2);
    transpose_multi_kernel<<<tb, 256, 0, stream>>>(p);
  }

  // K-pad zeroing
  pad_zero_kernel<<<(NTOT * 20 + 255) / 256, 256, 0, stream>>>(agghi, agglo, NTOT, KP1, 300);
  pad_zero_kernel<<<(4096 * 8 + 255) / 256, 256, 0, stream>>>(emAhi, emAlo, 4096, KP2, 600);

  // GCN
  aggregate_kernel<<<NTOT, 320, 0, stream>>>(xbuf16, agghi, agglo, row_ptr, src_s, w_s);
  launch_mfma(stream, agghi, agglo, KP1, w12hi, w12lo, KP1, NTOT, 300, KP1, nullptr, nullptr, 0,
              0, b1, 1, nullptr, h1f16, nullptr, 300, 2);  // h1 (f16 single)
  aggregate_kernel<<<NTOT, 320, 0, stream>>>(h1f16, agghi, agglo, row_ptr, src_s, w_s);
  pad_zero_kernel<<<(NTOT * 20 + 255) / 256, 256, 0, stream>>>(h2hi, h2lo, NTOT, KP1, 300);
  launch_mfma(stream, agghi, agglo, KP1, w12hi + 96000, w12lo + 96000, KP1, NTOT, 300, KP1,
              nullptr, nullptr, 0, 0, b2, 0, nullptr, h2hi, h2lo, KP1, 3);

  // q (single batched GEMM, M=4096, N=512: dirs 0|1), fp32 out
  launch_mfma(stream, h2hi, h2lo, KP1, qkvhi, qkvlo, KP1, 2 * BB, 512, KP1, idsAll, qAll, 512, 0,
              nullptr, 0, nullptr, nullptr, nullptr, 0, 2);

  // kv: one fused GEMM over both dirs, N=1024 = [k0|v0|k1|v1], f16 out
  launch_mfma(stream, h2hi, h2lo, KP1, qkvhi + 2 * 81920, qkvlo + 2 * 81920, KP1, NTOT, 1024,
              KP1, nullptr, nullptr, 0, 0, nullptr, 0, nullptr, kvAll, nullptr, 1024, 2);

  // attention: one launch, all 4 (dir,side) combos
  attention_kernel<<<dim3(BB, 4), 256, 0, stream>>>(
      qAll, kvAll,
      (const int*)d_in[20], (const int*)d_in[19],   // l_in
      (const int*)d_in[23], (const int*)d_in[22],   // l_out
      (const int*)d_in[26], (const int*)d_in[25],   // r_in
      (const int*)d_in[29], (const int*)d_in[28],   // r_out
      mask_norm, ctxAhi, ctxAlo);

  // Wo (batched): M=8192 over ctxAll, epilogue routes into emAll
  launch_mfma(stream, ctxAhi, ctxAlo, 256, wohi, wolo, 256, 4 * BB, 600, 256, nullptr, nullptr,
              0, 0, nullptr, 0, maskany, emAhi, emAlo, KP2, 3, 1);

  // proximity (batched M=4096: lem rows then rem rows — contiguous in d_out)
  float* lem = out + 1;
  float* rem = out + 1 + (size_t)BB * 600;
  launch_mfma(stream, emAhi, emAlo, KP2, wpxhi, wpxlo, KP2, 4096, 300, KP2, nullptr, lem, 600,
              300, bprox, 0, nullptr, nullptr, nullptr, 0, 3);
  gather_part_kernel<<<BB, 320, 0, stream>>>(h2hi, h2lo, l_ids, lem);
  gather_part_kernel<<<BB, 320, 0, stream>>>(h2hi, h2lo, r_ids, rem);

  // cosine similarity + fused loss
  rownorm_kernel<<<BB, 256, 0, stream>>>(lem, lnhi, lnlo);
  rownorm_kernel<<<BB, 256, 0, stream>>>(rem, rnhi, rnlo);
  launch_mfma(stream, lnhi, lnlo, KP2, rnhi, rnlo, KP2, BB, BB, KP2, nullptr, nullptr, 0, 0,
              nullptr, 0, nullptr, nullptr, nullptr, 0, 1, 0, 1, accum);
  finalize_kernel<<<1, 1, 0, stream>>>(accum, out);
}